// Round 1
// baseline (303.128 us; speedup 1.0000x reference)
//
#include <hip/hip_runtime.h>

typedef unsigned short u16;
typedef unsigned int u32;
typedef __bf16 bf16x8 __attribute__((ext_vector_type(8)));
typedef float f32x4 __attribute__((ext_vector_type(4)));
typedef u32 u32x4 __attribute__((ext_vector_type(4)));

#define DEVI __device__ __forceinline__

#if defined(__has_builtin)
#if __has_builtin(__builtin_amdgcn_exp2f)
#define EXP2F(x) __builtin_amdgcn_exp2f(x)
#endif
#endif
#ifndef EXP2F
#define EXP2F(x) exp2f(x)
#endif

DEVI u16 f2bf(float f) {
    u32 u = __builtin_bit_cast(u32, f);
    u = (u + 0x7FFFu + ((u >> 16) & 1u)) >> 16;
    return (u16)u;
}
DEVI float bf2f(u16 h) {
    u32 u = ((u32)h) << 16;
    return __builtin_bit_cast(float, u);
}
DEVI bf16x8 bc8(u32x4 u) { return __builtin_bit_cast(bf16x8, u); }

// q scale: dh^-0.5 * log2(e)  (bakes natural-exp into exp2)
#define QSCALE 0.18033688011112042f

// ---------------------------------------------------------------------------
// K0a: cast weights fp32 -> bf16
__global__ __launch_bounds__(256) void k_cast_w(const float* __restrict__ wq,
                                                const float* __restrict__ wo,
                                                u16* __restrict__ wqb, u16* __restrict__ wob) {
    int i = blockIdx.x * 256 + threadIdx.x;
    if (i < 196608) wqb[i] = f2bf(wq[i]);
    if (i < 65536) wob[i] = f2bf(wo[i]);
}

// ---------------------------------------------------------------------------
// K0b: transpose+cast x [b][c=256][p=4096] fp32 -> xt [b][p][c] bf16
__global__ __launch_bounds__(256) void k_tx(const float* __restrict__ x, u16* __restrict__ xt) {
    int pm = blockIdx.x, cm = blockIdx.y, b = blockIdx.z;
    int p0 = pm * 64, c0 = cm * 64;
    __shared__ float tile[64][65];
    int t = threadIdx.x;
#pragma unroll
    for (int it = 0; it < 16; ++it) {
        int idx = it * 256 + t;
        int cl = idx >> 6, pl = idx & 63;
        tile[cl][pl] = x[((size_t)(b * 256 + c0 + cl)) * 4096 + p0 + pl];
    }
    __syncthreads();
#pragma unroll
    for (int it = 0; it < 16; ++it) {
        int idx = it * 256 + t;
        int pl = idx >> 6, cl = idx & 63;
        xt[((size_t)(b * 4096 + p0 + pl)) * 256 + c0 + cl] = f2bf(tile[cl][pl]);
    }
}

// ---------------------------------------------------------------------------
// K1: QKV projection GEMM. C[p,o] = sum_c xt[p,c] * wqkv[o,c]
// A-frags (xt rows) from global; B tile (wqkv rows) staged in LDS.
// grid (64 pm, 12 on, 2 b), 256 thr. on -> tensor=on>>2 (q,k,v), head=on&3.
__global__ __launch_bounds__(256) void k_qkv(const u16* __restrict__ xt, const u16* __restrict__ wqb,
                                             u16* __restrict__ q, u16* __restrict__ k,
                                             u16* __restrict__ v) {
    int pm = blockIdx.x, on = blockIdx.y, b = blockIdx.z;
    int p0 = pm * 64, o0 = on * 64;
    __shared__ __align__(16) u16 Bt[64 * 264];
    int t = threadIdx.x;
    int wv = t >> 6, l = t & 63, quad = l >> 4, li = l & 15;

    u32x4 areg[8];
    const u32x4* arow = (const u32x4*)(xt + ((size_t)(b * 4096 + p0 + wv * 16 + li)) * 256);
#pragma unroll
    for (int kc = 0; kc < 8; ++kc) areg[kc] = arow[kc * 4 + quad];

    {
        int row = t >> 2, c0 = (t & 3) * 64;
        const u32x4* g = (const u32x4*)(wqb + (size_t)(o0 + row) * 256 + c0);
        u32x4* s = (u32x4*)(Bt + row * 264 + c0);
#pragma unroll
        for (int kk = 0; kk < 8; ++kk) s[kk] = g[kk];
    }
    __syncthreads();

    f32x4 acc[4] = {{0, 0, 0, 0}, {0, 0, 0, 0}, {0, 0, 0, 0}, {0, 0, 0, 0}};
#pragma unroll
    for (int kc = 0; kc < 8; ++kc) {
        bf16x8 a = bc8(areg[kc]);
#pragma unroll
        for (int ct = 0; ct < 4; ++ct) {
            bf16x8 bb = bc8(*(const u32x4*)(Bt + (ct * 16 + li) * 264 + kc * 32 + quad * 8));
            acc[ct] = __builtin_amdgcn_mfma_f32_16x16x32_bf16(a, bb, acc[ct], 0, 0, 0);
        }
    }

    int tensor = on >> 2, head = on & 3;
    u16* outp = (tensor == 0) ? q : ((tensor == 1) ? k : v);
    float sc = (tensor == 0) ? QSCALE : 1.0f;
#pragma unroll
    for (int ct = 0; ct < 4; ++ct)
#pragma unroll
        for (int r = 0; r < 4; ++r) {
            int p = p0 + wv * 16 + quad * 4 + r;
            int d = ct * 16 + li;
            outp[((size_t)((b * 4 + head) * 4096 + p)) * 64 + d] = f2bf(acc[ct][r] * sc);
        }
}

// ---------------------------------------------------------------------------
// K2: transpose v [bh][p][d] -> vt [bh][d][p]
__global__ __launch_bounds__(256) void k_tv(const u16* __restrict__ v, u16* __restrict__ vt) {
    int pm = blockIdx.x, bh = blockIdx.y;
    int p0 = pm * 64;
    __shared__ u16 tile[64][65];
    int t = threadIdx.x;
#pragma unroll
    for (int it = 0; it < 16; ++it) {
        int idx = it * 256 + t;
        int pl = idx >> 6, d = idx & 63;
        tile[pl][d] = v[((size_t)(bh * 4096 + p0 + pl)) * 64 + d];
    }
    __syncthreads();
#pragma unroll
    for (int it = 0; it < 16; ++it) {
        int idx = it * 256 + t;
        int dl = idx >> 6, pl = idx & 63;
        vt[((size_t)(bh * 64 + dl)) * 4096 + p0 + pl] = tile[pl][dl];
    }
}

// ---------------------------------------------------------------------------
// K2b: bias tables. W[bh,p,jw] = q_p . rel_width[jw - y + 63]; Hh likewise with x.
// q already carries QSCALE so tables are in exp2 units. grid (4096 p, 8 bh), 128 thr.
__global__ __launch_bounds__(128) void k_bias(const u16* __restrict__ q,
                                              const float* __restrict__ relh,
                                              const float* __restrict__ relw,
                                              float* __restrict__ W, float* __restrict__ Hh) {
    int p = blockIdx.x, bh = blockIdx.y;
    __shared__ float qs[64];
    int t = threadIdx.x;
    if (t < 64) qs[t] = bf2f(q[((size_t)(bh * 4096 + p)) * 64 + t]);
    __syncthreads();
    int y = p & 63, x = p >> 6;
    int half = t >> 6, j = t & 63;
    const float* rel = half ? relh : relw;
    int ridx = j - (half ? x : y) + 63;
    const float* rr = rel + (size_t)ridx * 64;
    float s = 0.f;
#pragma unroll
    for (int d = 0; d < 64; ++d) s += qs[d] * rr[d];
    float* outp = half ? Hh : W;
    outp[((size_t)(bh * 4096 + p)) * 64 + j] = s;
}

// ---------------------------------------------------------------------------
// K3: flash attention. grid (64 pm, 8 bh), 256 thr = 4 waves, 16 q-rows/wave.
// No-max online softmax (logits bounded), exp2 domain, l accumulated per lane.
__global__ __launch_bounds__(256) void k_flash(const u16* __restrict__ q, const u16* __restrict__ kg,
                                               const u16* __restrict__ vt,
                                               const float* __restrict__ W,
                                               const float* __restrict__ Hh, u16* __restrict__ O) {
    int pm = blockIdx.x, bh = blockIdx.y;
    int p0 = pm * 64;
    __shared__ __align__(16) u16 Kt[64 * 72];
    __shared__ __align__(16) u16 Vl[64 * 72];
    __shared__ __align__(16) u16 Pl[4][16 * 72];
    __shared__ __align__(16) float Hl[64 * 68];
    int t = threadIdx.x, wv = t >> 6, l = t & 63, quad = l >> 4, li = l & 15;

    // Q A-frags (2 x K=32) from global
    u32x4 aq[2];
    const u32x4* qrow = (const u32x4*)(q + ((size_t)(bh * 4096 + p0 + wv * 16 + li)) * 64);
    aq[0] = qrow[quad];
    aq[1] = qrow[4 + quad];

    // W bias into registers: element (ct,r) of each C-frag
    float wb[4][4];
#pragma unroll
    for (int ct = 0; ct < 4; ++ct)
#pragma unroll
        for (int r = 0; r < 4; ++r)
            wb[ct][r] = W[((size_t)(bh * 4096 + p0 + wv * 16 + quad * 4 + r)) * 64 + ct * 16 + li];

    // stage Hh tile [64 rows p][64 jh]
    {
        int row = t >> 2, c0 = (t & 3) * 16;
        const float* g = Hh + ((size_t)(bh * 4096 + p0 + row)) * 64 + c0;
#pragma unroll
        for (int kk = 0; kk < 4; ++kk)
            *(u32x4*)(Hl + row * 68 + c0 + kk * 4) = *(const u32x4*)(g + kk * 4);
    }

    f32x4 oacc[4] = {{0, 0, 0, 0}, {0, 0, 0, 0}, {0, 0, 0, 0}, {0, 0, 0, 0}};
    float lsum[4] = {0.f, 0.f, 0.f, 0.f};
    __syncthreads();

    int srow = t >> 2, sc0 = (t & 3) * 16;
    for (int kt = 0; kt < 64; ++kt) {
        int j0 = kt * 64;
        // stage K tile [j][d] and Vt tile [d][j]
        {
            const u32x4* gk = (const u32x4*)(kg + ((size_t)(bh * 4096 + j0 + srow)) * 64 + sc0);
            u32x4* sk = (u32x4*)(Kt + srow * 72 + sc0);
            sk[0] = gk[0];
            sk[1] = gk[1];
            const u32x4* gv = (const u32x4*)(vt + ((size_t)(bh * 64 + srow)) * 4096 + j0 + sc0);
            u32x4* sv = (u32x4*)(Vl + srow * 72 + sc0);
            sv[0] = gv[0];
            sv[1] = gv[1];
        }
        __syncthreads();

        // S = Q K^T  (16x64 per wave)
        f32x4 s[4] = {{0, 0, 0, 0}, {0, 0, 0, 0}, {0, 0, 0, 0}, {0, 0, 0, 0}};
#pragma unroll
        for (int kc = 0; kc < 2; ++kc) {
            bf16x8 a = bc8(aq[kc]);
#pragma unroll
            for (int ct = 0; ct < 4; ++ct) {
                bf16x8 bb = bc8(*(const u32x4*)(Kt + (ct * 16 + li) * 72 + kc * 32 + quad * 8));
                s[ct] = __builtin_amdgcn_mfma_f32_16x16x32_bf16(a, bb, s[ct], 0, 0, 0);
            }
        }

        // bias + exp2 + write P (per-wave LDS region, same-wave read later)
        u16* P = Pl[wv];
#pragma unroll
        for (int ct = 0; ct < 4; ++ct)
#pragma unroll
            for (int r = 0; r < 4; ++r) {
                float hh = Hl[(wv * 16 + quad * 4 + r) * 68 + kt];
                float pe = EXP2F(s[ct][r] + wb[ct][r] + hh);
                lsum[r] += pe;
                P[(quad * 4 + r) * 72 + ct * 16 + li] = f2bf(pe);
            }

        // O += P V
#pragma unroll
        for (int kc = 0; kc < 2; ++kc) {
            bf16x8 a = bc8(*(const u32x4*)(P + li * 72 + kc * 32 + quad * 8));
#pragma unroll
            for (int ct = 0; ct < 4; ++ct) {
                bf16x8 bb = bc8(*(const u32x4*)(Vl + (ct * 16 + li) * 72 + kc * 32 + quad * 8));
                oacc[ct] = __builtin_amdgcn_mfma_f32_16x16x32_bf16(a, bb, oacc[ct], 0, 0, 0);
            }
        }
        __syncthreads();
    }

    // full row sums across the 16 lanes of each quad-group, then divide
#pragma unroll
    for (int r = 0; r < 4; ++r) {
        float s = lsum[r];
        s += __shfl_xor(s, 1, 16);
        s += __shfl_xor(s, 2, 16);
        s += __shfl_xor(s, 4, 16);
        s += __shfl_xor(s, 8, 16);
        lsum[r] = 1.0f / s;
    }
#pragma unroll
    for (int ct = 0; ct < 4; ++ct)
#pragma unroll
        for (int r = 0; r < 4; ++r) {
            int p = p0 + wv * 16 + quad * 4 + r;
            O[((size_t)(bh * 4096 + p)) * 64 + ct * 16 + li] = f2bf(oacc[ct][r] * lsum[r]);
        }
}

// ---------------------------------------------------------------------------
// K4: out projection + residual. C[co,p] = sum_c wout[co,c] * O[b,p,c] ; += x
// A-frags (wout rows) from global; B tile = O rows (c-major via head chunks) in LDS.
// grid (64 pm, 4 com, 2 b), 256 thr. Output stores lane-contiguous in p.
__global__ __launch_bounds__(256) void k_out(const u16* __restrict__ wob, const u16* __restrict__ O,
                                             const float* __restrict__ x, float* __restrict__ out) {
    int pm = blockIdx.x, com = blockIdx.y, b = blockIdx.z;
    int p0 = pm * 64, co0 = com * 64;
    __shared__ __align__(16) u16 Bt[64 * 264];
    int t = threadIdx.x, wv = t >> 6, l = t & 63, quad = l >> 4, li = l & 15;

    u32x4 areg[8];
    const u32x4* arow = (const u32x4*)(wob + (size_t)(co0 + wv * 16 + li) * 256);
#pragma unroll
    for (int kc = 0; kc < 8; ++kc) areg[kc] = arow[kc * 4 + quad];

    {
        int row = t >> 2, head = t & 3;
        const u32x4* g = (const u32x4*)(O + ((size_t)((b * 4 + head) * 4096 + p0 + row)) * 64);
        u32x4* s = (u32x4*)(Bt + row * 264 + head * 64);
#pragma unroll
        for (int kk = 0; kk < 8; ++kk) s[kk] = g[kk];
    }
    __syncthreads();

    f32x4 acc[4] = {{0, 0, 0, 0}, {0, 0, 0, 0}, {0, 0, 0, 0}, {0, 0, 0, 0}};
#pragma unroll
    for (int kc = 0; kc < 8; ++kc) {
        bf16x8 a = bc8(areg[kc]);
#pragma unroll
        for (int ct = 0; ct < 4; ++ct) {
            bf16x8 bb = bc8(*(const u32x4*)(Bt + (ct * 16 + li) * 264 + kc * 32 + quad * 8));
            acc[ct] = __builtin_amdgcn_mfma_f32_16x16x32_bf16(a, bb, acc[ct], 0, 0, 0);
        }
    }

#pragma unroll
    for (int ct = 0; ct < 4; ++ct)
#pragma unroll
        for (int r = 0; r < 4; ++r) {
            size_t idx = ((size_t)(b * 256 + co0 + wv * 16 + quad * 4 + r)) * 4096 + p0 + ct * 16 + li;
            out[idx] = acc[ct][r] + x[idx];
        }
}

// ---------------------------------------------------------------------------
extern "C" void kernel_launch(void* const* d_in, const int* in_sizes, int n_in, void* d_out,
                              int out_size, void* d_ws, size_t ws_size, hipStream_t stream) {
    const float* x = (const float*)d_in[0];
    const float* wqkv = (const float*)d_in[1];
    const float* wout = (const float*)d_in[2];
    const float* relh = (const float*)d_in[3];
    const float* relw = (const float*)d_in[4];
    float* out = (float*)d_out;
    char* ws = (char*)d_ws;

    u16* xt = (u16*)(ws + 0);              // 2*4096*256*2   = 4,194,304
    u16* wqb = (u16*)(ws + 4194304);       // 768*256*2      =   393,216
    u16* wob = (u16*)(ws + 4587520);       // 256*256*2      =   131,072
    u16* qb = (u16*)(ws + 4718592);        // 8*4096*64*2    = 4,194,304
    u16* kb = (u16*)(ws + 8912896);        // 4,194,304
    u16* vb = (u16*)(ws + 13107200);       // 4,194,304
    u16* vtb = (u16*)(ws + 17301504);      // 4,194,304
    float* Wb = (float*)(ws + 21495808);   // 8*4096*64*4    = 8,388,608
    float* Hb = (float*)(ws + 29884416);   // 8,388,608
    u16* Ob = (u16*)(ws + 38273024);       // 4,194,304  (end ~42.5 MB)

    k_cast_w<<<1024, 256, 0, stream>>>(wqkv, wout, wqb, wob);
    k_tx<<<dim3(64, 4, 2), 256, 0, stream>>>(x, xt);
    k_qkv<<<dim3(64, 12, 2), 256, 0, stream>>>(xt, wqb, qb, kb, vb);
    k_tv<<<dim3(64, 8), 256, 0, stream>>>(vb, vtb);
    k_bias<<<dim3(4096, 8), 128, 0, stream>>>(qb, relh, relw, Wb, Hb);
    k_flash<<<dim3(64, 8), 256, 0, stream>>>(qb, kb, vtb, Wb, Hb, Ob);
    k_out<<<dim3(64, 4, 2), 256, 0, stream>>>(wob, Ob, x, out);
}

// Round 2
// 191.380 us; speedup vs baseline: 1.5839x; 1.5839x over previous
//
#include <hip/hip_runtime.h>

typedef unsigned short u16;
typedef unsigned int u32;
typedef __bf16 bf16x8 __attribute__((ext_vector_type(8)));
typedef float f32x4 __attribute__((ext_vector_type(4)));
typedef u32 u32x4 __attribute__((ext_vector_type(4)));

#define DEVI __device__ __forceinline__

#if defined(__has_builtin)
#if __has_builtin(__builtin_amdgcn_exp2f)
#define EXP2F(x) __builtin_amdgcn_exp2f(x)
#endif
#endif
#ifndef EXP2F
#define EXP2F(x) exp2f(x)
#endif

DEVI u16 f2bf(float f) {
    u32 u = __builtin_bit_cast(u32, f);
    u = (u + 0x7FFFu + ((u >> 16) & 1u)) >> 16;
    return (u16)u;
}
DEVI float bf2f(u16 h) {
    u32 u = ((u32)h) << 16;
    return __builtin_bit_cast(float, u);
}
DEVI bf16x8 bc8(u32x4 u) { return __builtin_bit_cast(bf16x8, u); }

// q scale: dh^-0.5 * log2(e)  (bakes natural-exp into exp2)
#define QSCALE 0.18033688011112042f

// ---------------------------------------------------------------------------
// K0a: cast weights fp32 -> bf16 (+ rel tables, zero-padded to 128 rows)
__global__ __launch_bounds__(256) void k_cast_w(const float* __restrict__ wq,
                                                const float* __restrict__ wo,
                                                const float* __restrict__ relh,
                                                const float* __restrict__ relw,
                                                u16* __restrict__ wqb, u16* __restrict__ wob,
                                                u16* __restrict__ relhb, u16* __restrict__ relwb) {
    int i = blockIdx.x * 256 + threadIdx.x;
    if (i < 196608) wqb[i] = f2bf(wq[i]);
    if (i < 65536) wob[i] = f2bf(wo[i]);
    if (i < 8192) {
        relhb[i] = (i < 8128) ? f2bf(relh[i]) : (u16)0;
        relwb[i] = (i < 8128) ? f2bf(relw[i]) : (u16)0;
    }
}

// ---------------------------------------------------------------------------
// K0b: transpose+cast x [b][c=256][p=4096] fp32 -> xt [b][p][c] bf16
__global__ __launch_bounds__(256) void k_tx(const float* __restrict__ x, u16* __restrict__ xt) {
    int pm = blockIdx.x, cm = blockIdx.y, b = blockIdx.z;
    int p0 = pm * 64, c0 = cm * 64;
    __shared__ float tile[64][65];
    int t = threadIdx.x;
#pragma unroll
    for (int it = 0; it < 16; ++it) {
        int idx = it * 256 + t;
        int cl = idx >> 6, pl = idx & 63;
        tile[cl][pl] = x[((size_t)(b * 256 + c0 + cl)) * 4096 + p0 + pl];
    }
    __syncthreads();
#pragma unroll
    for (int it = 0; it < 16; ++it) {
        int idx = it * 256 + t;
        int pl = idx >> 6, cl = idx & 63;
        xt[((size_t)(b * 4096 + p0 + pl)) * 256 + c0 + cl] = f2bf(tile[cl][pl]);
    }
}

// ---------------------------------------------------------------------------
// K1: QKV projection GEMM. C[p,o] = sum_c xt[p,c] * wqkv[o,c]
__global__ __launch_bounds__(256) void k_qkv(const u16* __restrict__ xt, const u16* __restrict__ wqb,
                                             u16* __restrict__ q, u16* __restrict__ k,
                                             u16* __restrict__ v) {
    int pm = blockIdx.x, on = blockIdx.y, b = blockIdx.z;
    int p0 = pm * 64, o0 = on * 64;
    __shared__ __align__(16) u16 Bt[64 * 264];
    int t = threadIdx.x;
    int wv = t >> 6, l = t & 63, quad = l >> 4, li = l & 15;

    u32x4 areg[8];
    const u32x4* arow = (const u32x4*)(xt + ((size_t)(b * 4096 + p0 + wv * 16 + li)) * 256);
#pragma unroll
    for (int kc = 0; kc < 8; ++kc) areg[kc] = arow[kc * 4 + quad];

    {
        int row = t >> 2, c0 = (t & 3) * 64;
        const u32x4* g = (const u32x4*)(wqb + (size_t)(o0 + row) * 256 + c0);
        u32x4* s = (u32x4*)(Bt + row * 264 + c0);
#pragma unroll
        for (int kk = 0; kk < 8; ++kk) s[kk] = g[kk];
    }
    __syncthreads();

    f32x4 acc[4] = {{0, 0, 0, 0}, {0, 0, 0, 0}, {0, 0, 0, 0}, {0, 0, 0, 0}};
#pragma unroll
    for (int kc = 0; kc < 8; ++kc) {
        bf16x8 a = bc8(areg[kc]);
#pragma unroll
        for (int ct = 0; ct < 4; ++ct) {
            bf16x8 bb = bc8(*(const u32x4*)(Bt + (ct * 16 + li) * 264 + kc * 32 + quad * 8));
            acc[ct] = __builtin_amdgcn_mfma_f32_16x16x32_bf16(a, bb, acc[ct], 0, 0, 0);
        }
    }

    int tensor = on >> 2, head = on & 3;
    u16* outp = (tensor == 0) ? q : ((tensor == 1) ? k : v);
    float sc = (tensor == 0) ? QSCALE : 1.0f;
#pragma unroll
    for (int ct = 0; ct < 4; ++ct)
#pragma unroll
        for (int r = 0; r < 4; ++r) {
            int p = p0 + wv * 16 + quad * 4 + r;
            int d = ct * 16 + li;
            outp[((size_t)((b * 4 + head) * 4096 + p)) * 64 + d] = f2bf(acc[ct][r] * sc);
        }
}

// ---------------------------------------------------------------------------
// K2: transpose v [bh][p][d] -> vt [bh][d][p]
__global__ __launch_bounds__(256) void k_tv(const u16* __restrict__ v, u16* __restrict__ vt) {
    int pm = blockIdx.x, bh = blockIdx.y;
    int p0 = pm * 64;
    __shared__ u16 tile[64][65];
    int t = threadIdx.x;
#pragma unroll
    for (int it = 0; it < 16; ++it) {
        int idx = it * 256 + t;
        int pl = idx >> 6, d = idx & 63;
        tile[pl][d] = v[((size_t)(bh * 4096 + p0 + pl)) * 64 + d];
    }
    __syncthreads();
#pragma unroll
    for (int it = 0; it < 16; ++it) {
        int idx = it * 256 + t;
        int dl = idx >> 6, pl = idx & 63;
        vt[((size_t)(bh * 64 + dl)) * 4096 + p0 + pl] = tile[pl][dl];
    }
}

// ---------------------------------------------------------------------------
// K2b (NEW): bias tables via MFMA. R[p, r] = q_p . rel[r], r in [0,128) (row 127 zero).
// Within a block all 64 p-rows share x = p>>6 = pm, so the rel_to_abs gather is
// applied AT STORE TIME: only absolute columns jw/jh in [0,64) are written.
//   z=0: Wabs[p][jw] = q_p . rel_w[jw - (p&63) + 63]   (per-lane shift: y = row)
//   z=1: Habs[p][jh] = q_p . rel_h[jh - pm + 63]       (uniform shift per block)
// grid (64 pm, 8 bh, 2 z), 256 thr. Output bf16 (exp2 units; q carries QSCALE).
__global__ __launch_bounds__(256) void k_rel(const u16* __restrict__ q,
                                             const u16* __restrict__ relwb,
                                             const u16* __restrict__ relhb,
                                             u16* __restrict__ Wabs, u16* __restrict__ Habs) {
    int pm = blockIdx.x, bh = blockIdx.y, z = blockIdx.z;
    int p0 = pm * 64;
    const u16* rel = z ? relhb : relwb;
    u16* outp = z ? Habs : Wabs;
    __shared__ __align__(16) u16 Ls[128 * 72];
    int t = threadIdx.x, wv = t >> 6, l = t & 63, quad = l >> 4, li = l & 15;

    // stage rel table (128 rows x 64 d) into LDS
    {
        int row = t >> 1, half = t & 1;
        const u32x4* g = (const u32x4*)(rel + row * 64 + half * 32);
        u32x4* s = (u32x4*)(Ls + row * 72 + half * 32);
#pragma unroll
        for (int kk = 0; kk < 4; ++kk) s[kk] = g[kk];
    }

    u32x4 aq[2];
    const u32x4* qrow = (const u32x4*)(q + ((size_t)(bh * 4096 + p0 + wv * 16 + li)) * 64);
    aq[0] = qrow[quad];
    aq[1] = qrow[4 + quad];
    __syncthreads();

    f32x4 acc[8];
#pragma unroll
    for (int ct = 0; ct < 8; ++ct) acc[ct] = (f32x4){0.f, 0.f, 0.f, 0.f};
#pragma unroll
    for (int kc = 0; kc < 2; ++kc) {
        bf16x8 a = bc8(aq[kc]);
#pragma unroll
        for (int ct = 0; ct < 8; ++ct) {
            bf16x8 bb = bc8(*(const u32x4*)(Ls + (ct * 16 + li) * 72 + kc * 32 + quad * 8));
            acc[ct] = __builtin_amdgcn_mfma_f32_16x16x32_bf16(a, bb, acc[ct], 0, 0, 0);
        }
    }

    // scatter-store only valid absolute columns
#pragma unroll
    for (int ct = 0; ct < 8; ++ct)
#pragma unroll
        for (int r = 0; r < 4; ++r) {
            int row = wv * 16 + quad * 4 + r;       // p - p0
            int p = p0 + row;
            int c = ct * 16 + li;                   // relative index r
            int shift = z ? pm : row;               // x or y
            int j = c - 63 + shift;                 // absolute jh/jw
            if (j >= 0 && j < 64)
                outp[((size_t)(bh * 4096 + p)) * 64 + j] = f2bf(acc[ct][r]);
        }
}

// ---------------------------------------------------------------------------
// K3: flash attention. grid (64 pm, 8 bh), 256 thr = 4 waves, 16 q-rows/wave.
// No-max online softmax (logits bounded), exp2 domain, l accumulated per lane.
__global__ __launch_bounds__(256) void k_flash(const u16* __restrict__ q, const u16* __restrict__ kg,
                                               const u16* __restrict__ vt,
                                               const u16* __restrict__ Wabs,
                                               const u16* __restrict__ Habs, u16* __restrict__ O) {
    int pm = blockIdx.x, bh = blockIdx.y;
    int p0 = pm * 64;
    __shared__ __align__(16) u16 Kt[64 * 72];
    __shared__ __align__(16) u16 Vl[64 * 72];
    __shared__ __align__(16) u16 Pl[4][16 * 72];
    __shared__ __align__(16) float Hl[64 * 68];
    int t = threadIdx.x, wv = t >> 6, l = t & 63, quad = l >> 4, li = l & 15;

    // Q A-frags (2 x K=32) from global
    u32x4 aq[2];
    const u32x4* qrow = (const u32x4*)(q + ((size_t)(bh * 4096 + p0 + wv * 16 + li)) * 64);
    aq[0] = qrow[quad];
    aq[1] = qrow[4 + quad];

    // W bias into registers: element (ct,r) of each C-frag (bf16 table)
    float wb[4][4];
#pragma unroll
    for (int ct = 0; ct < 4; ++ct)
#pragma unroll
        for (int r = 0; r < 4; ++r)
            wb[ct][r] = bf2f(Wabs[((size_t)(bh * 4096 + p0 + wv * 16 + quad * 4 + r)) * 64 + ct * 16 + li]);

    // stage Habs tile [64 rows p][64 jh], bf16 -> fp32 in LDS
    {
        int row = t >> 2, c0 = (t & 3) * 16;
        const u16* g = Habs + ((size_t)(bh * 4096 + p0 + row)) * 64 + c0;
#pragma unroll
        for (int kk = 0; kk < 16; ++kk) Hl[row * 68 + c0 + kk] = bf2f(g[kk]);
    }

    f32x4 oacc[4] = {{0, 0, 0, 0}, {0, 0, 0, 0}, {0, 0, 0, 0}, {0, 0, 0, 0}};
    float lsum[4] = {0.f, 0.f, 0.f, 0.f};
    __syncthreads();

    int srow = t >> 2, sc0 = (t & 3) * 16;
    for (int kt = 0; kt < 64; ++kt) {
        int j0 = kt * 64;
        // stage K tile [j][d] and Vt tile [d][j]
        {
            const u32x4* gk = (const u32x4*)(kg + ((size_t)(bh * 4096 + j0 + srow)) * 64 + sc0);
            u32x4* sk = (u32x4*)(Kt + srow * 72 + sc0);
            sk[0] = gk[0];
            sk[1] = gk[1];
            const u32x4* gv = (const u32x4*)(vt + ((size_t)(bh * 64 + srow)) * 4096 + j0 + sc0);
            u32x4* sv = (u32x4*)(Vl + srow * 72 + sc0);
            sv[0] = gv[0];
            sv[1] = gv[1];
        }
        __syncthreads();

        // S = Q K^T  (16x64 per wave)
        f32x4 s[4] = {{0, 0, 0, 0}, {0, 0, 0, 0}, {0, 0, 0, 0}, {0, 0, 0, 0}};
#pragma unroll
        for (int kc = 0; kc < 2; ++kc) {
            bf16x8 a = bc8(aq[kc]);
#pragma unroll
            for (int ct = 0; ct < 4; ++ct) {
                bf16x8 bb = bc8(*(const u32x4*)(Kt + (ct * 16 + li) * 72 + kc * 32 + quad * 8));
                s[ct] = __builtin_amdgcn_mfma_f32_16x16x32_bf16(a, bb, s[ct], 0, 0, 0);
            }
        }

        // bias + exp2 + write P (per-wave LDS region, same-wave read later)
        u16* P = Pl[wv];
#pragma unroll
        for (int ct = 0; ct < 4; ++ct)
#pragma unroll
            for (int r = 0; r < 4; ++r) {
                float hh = Hl[(wv * 16 + quad * 4 + r) * 68 + kt];
                float pe = EXP2F(s[ct][r] + wb[ct][r] + hh);
                lsum[r] += pe;
                P[(quad * 4 + r) * 72 + ct * 16 + li] = f2bf(pe);
            }

        // O += P V
#pragma unroll
        for (int kc = 0; kc < 2; ++kc) {
            bf16x8 a = bc8(*(const u32x4*)(P + li * 72 + kc * 32 + quad * 8));
#pragma unroll
            for (int ct = 0; ct < 4; ++ct) {
                bf16x8 bb = bc8(*(const u32x4*)(Vl + (ct * 16 + li) * 72 + kc * 32 + quad * 8));
                oacc[ct] = __builtin_amdgcn_mfma_f32_16x16x32_bf16(a, bb, oacc[ct], 0, 0, 0);
            }
        }
        __syncthreads();
    }

    // full row sums across the 16 lanes of each quad-group, then divide
#pragma unroll
    for (int r = 0; r < 4; ++r) {
        float s = lsum[r];
        s += __shfl_xor(s, 1, 16);
        s += __shfl_xor(s, 2, 16);
        s += __shfl_xor(s, 4, 16);
        s += __shfl_xor(s, 8, 16);
        lsum[r] = 1.0f / s;
    }
#pragma unroll
    for (int ct = 0; ct < 4; ++ct)
#pragma unroll
        for (int r = 0; r < 4; ++r) {
            int p = p0 + wv * 16 + quad * 4 + r;
            O[((size_t)(bh * 4096 + p)) * 64 + ct * 16 + li] = f2bf(oacc[ct][r] * lsum[r]);
        }
}

// ---------------------------------------------------------------------------
// K4: out projection + residual. C[co,p] = sum_c wout[co,c] * O[b,p,c] ; += x
__global__ __launch_bounds__(256) void k_out(const u16* __restrict__ wob, const u16* __restrict__ O,
                                             const float* __restrict__ x, float* __restrict__ out) {
    int pm = blockIdx.x, com = blockIdx.y, b = blockIdx.z;
    int p0 = pm * 64, co0 = com * 64;
    __shared__ __align__(16) u16 Bt[64 * 264];
    int t = threadIdx.x, wv = t >> 6, l = t & 63, quad = l >> 4, li = l & 15;

    u32x4 areg[8];
    const u32x4* arow = (const u32x4*)(wob + (size_t)(co0 + wv * 16 + li) * 256);
#pragma unroll
    for (int kc = 0; kc < 8; ++kc) areg[kc] = arow[kc * 4 + quad];

    {
        int row = t >> 2, head = t & 3;
        const u32x4* g = (const u32x4*)(O + ((size_t)((b * 4 + head) * 4096 + p0 + row)) * 64);
        u32x4* s = (u32x4*)(Bt + row * 264 + head * 64);
#pragma unroll
        for (int kk = 0; kk < 8; ++kk) s[kk] = g[kk];
    }
    __syncthreads();

    f32x4 acc[4] = {{0, 0, 0, 0}, {0, 0, 0, 0}, {0, 0, 0, 0}, {0, 0, 0, 0}};
#pragma unroll
    for (int kc = 0; kc < 8; ++kc) {
        bf16x8 a = bc8(areg[kc]);
#pragma unroll
        for (int ct = 0; ct < 4; ++ct) {
            bf16x8 bb = bc8(*(const u32x4*)(Bt + (ct * 16 + li) * 264 + kc * 32 + quad * 8));
            acc[ct] = __builtin_amdgcn_mfma_f32_16x16x32_bf16(a, bb, acc[ct], 0, 0, 0);
        }
    }

#pragma unroll
    for (int ct = 0; ct < 4; ++ct)
#pragma unroll
        for (int r = 0; r < 4; ++r) {
            size_t idx = ((size_t)(b * 256 + co0 + wv * 16 + quad * 4 + r)) * 4096 + p0 + ct * 16 + li;
            out[idx] = acc[ct][r] + x[idx];
        }
}

// ---------------------------------------------------------------------------
extern "C" void kernel_launch(void* const* d_in, const int* in_sizes, int n_in, void* d_out,
                              int out_size, void* d_ws, size_t ws_size, hipStream_t stream) {
    const float* x = (const float*)d_in[0];
    const float* wqkv = (const float*)d_in[1];
    const float* wout = (const float*)d_in[2];
    const float* relh = (const float*)d_in[3];
    const float* relw = (const float*)d_in[4];
    float* out = (float*)d_out;
    char* ws = (char*)d_ws;

    u16* xt = (u16*)(ws + 0);               // 4,194,304
    u16* wqb = (u16*)(ws + 4194304);        //   393,216
    u16* wob = (u16*)(ws + 4587520);        //   131,072
    u16* relwb = (u16*)(ws + 4718592);      //    16,384
    u16* relhb = (u16*)(ws + 4734976);      //    16,384
    u16* qb = (u16*)(ws + 4751360);         // 4,194,304
    u16* kb = (u16*)(ws + 8945664);         // 4,194,304
    u16* vb = (u16*)(ws + 13139968);        // 4,194,304
    u16* vtb = (u16*)(ws + 17334272);       // 4,194,304
    u16* Wabs = (u16*)(ws + 21528576);      // 4,194,304
    u16* Habs = (u16*)(ws + 25722880);      // 4,194,304
    u16* Ob = (u16*)(ws + 29917184);        // 4,194,304  (end ~34.1 MB)

    k_cast_w<<<1024, 256, 0, stream>>>(wqkv, wout, relh, relw, wqb, wob, relhb, relwb);
    k_tx<<<dim3(64, 4, 2), 256, 0, stream>>>(x, xt);
    k_qkv<<<dim3(64, 12, 2), 256, 0, stream>>>(xt, wqb, qb, kb, vb);
    k_tv<<<dim3(64, 8), 256, 0, stream>>>(vb, vtb);
    k_rel<<<dim3(64, 8, 2), 256, 0, stream>>>(qb, relwb, relhb, Wabs, Habs);
    k_flash<<<dim3(64, 8), 256, 0, stream>>>(qb, kb, vtb, Wabs, Habs, Ob);
    k_out<<<dim3(64, 4, 2), 256, 0, stream>>>(wob, Ob, x, out);
}

// Round 3
// 171.609 us; speedup vs baseline: 1.7664x; 1.1152x over previous
//
#include <hip/hip_runtime.h>

typedef unsigned short u16;
typedef unsigned int u32;
typedef __bf16 bf16x8 __attribute__((ext_vector_type(8)));
typedef float f32x4 __attribute__((ext_vector_type(4)));
typedef u32 u32x4 __attribute__((ext_vector_type(4)));

#define DEVI __device__ __forceinline__

#if defined(__has_builtin)
#if __has_builtin(__builtin_amdgcn_exp2f)
#define EXP2F(x) __builtin_amdgcn_exp2f(x)
#endif
#endif
#ifndef EXP2F
#define EXP2F(x) exp2f(x)
#endif

#define MFMA16(a, b, c) __builtin_amdgcn_mfma_f32_16x16x32_bf16(a, b, c, 0, 0, 0)

DEVI u16 f2bf(float f) {
    u32 u = __builtin_bit_cast(u32, f);
    u = (u + 0x7FFFu + ((u >> 16) & 1u)) >> 16;
    return (u16)u;
}
DEVI float bf2f(u16 h) {
    u32 u = ((u32)h) << 16;
    return __builtin_bit_cast(float, u);
}
DEVI bf16x8 bc8(u32x4 u) { return __builtin_bit_cast(bf16x8, u); }

// q scale: dh^-0.5 * log2(e)  (bakes natural-exp into exp2)
#define QSCALE 0.18033688011112042f

// ---------------------------------------------------------------------------
// K0a: cast weights fp32 -> bf16 (+ rel tables, zero-padded to 128 rows)
__global__ __launch_bounds__(256) void k_cast_w(const float* __restrict__ wq,
                                                const float* __restrict__ wo,
                                                const float* __restrict__ relh,
                                                const float* __restrict__ relw,
                                                u16* __restrict__ wqb, u16* __restrict__ wob,
                                                u16* __restrict__ relhb, u16* __restrict__ relwb) {
    int i = blockIdx.x * 256 + threadIdx.x;
    if (i < 196608) wqb[i] = f2bf(wq[i]);
    if (i < 65536) wob[i] = f2bf(wo[i]);
    if (i < 8192) {
        relhb[i] = (i < 8128) ? f2bf(relh[i]) : (u16)0;
        relwb[i] = (i < 8128) ? f2bf(relw[i]) : (u16)0;
    }
}

// ---------------------------------------------------------------------------
// K0b: transpose+cast x [b][c=256][p=4096] fp32 -> xt [b][p][c] bf16
__global__ __launch_bounds__(256) void k_tx(const float* __restrict__ x, u16* __restrict__ xt) {
    int pm = blockIdx.x, cm = blockIdx.y, b = blockIdx.z;
    int p0 = pm * 64, c0 = cm * 64;
    __shared__ float tile[64][65];
    int t = threadIdx.x;
#pragma unroll
    for (int it = 0; it < 16; ++it) {
        int idx = it * 256 + t;
        int cl = idx >> 6, pl = idx & 63;
        tile[cl][pl] = x[((size_t)(b * 256 + c0 + cl)) * 4096 + p0 + pl];
    }
    __syncthreads();
#pragma unroll
    for (int it = 0; it < 16; ++it) {
        int idx = it * 256 + t;
        int pl = idx >> 6, cl = idx & 63;
        xt[((size_t)(b * 4096 + p0 + pl)) * 256 + c0 + cl] = f2bf(tile[cl][pl]);
    }
}

// ---------------------------------------------------------------------------
// K1: QKV projection GEMM. C[p,o] = sum_c xt[p,c] * wqkv[o,c]
// tensor==2 (v) blocks transpose through LDS and store vt[bh][d][p] directly.
__global__ __launch_bounds__(256) void k_qkv(const u16* __restrict__ xt, const u16* __restrict__ wqb,
                                             u16* __restrict__ q, u16* __restrict__ k,
                                             u16* __restrict__ vt) {
    int pm = blockIdx.x, on = blockIdx.y, b = blockIdx.z;
    int p0 = pm * 64, o0 = on * 64;
    __shared__ __align__(16) u16 Bt[64 * 264];
    int t = threadIdx.x;
    int wv = t >> 6, l = t & 63, quad = l >> 4, li = l & 15;

    u32x4 areg[8];
    const u32x4* arow = (const u32x4*)(xt + ((size_t)(b * 4096 + p0 + wv * 16 + li)) * 256);
#pragma unroll
    for (int kc = 0; kc < 8; ++kc) areg[kc] = arow[kc * 4 + quad];

    {
        int row = t >> 2, c0 = (t & 3) * 64;
        const u32x4* g = (const u32x4*)(wqb + (size_t)(o0 + row) * 256 + c0);
        u32x4* s = (u32x4*)(Bt + row * 264 + c0);
#pragma unroll
        for (int kk = 0; kk < 8; ++kk) s[kk] = g[kk];
    }
    __syncthreads();

    f32x4 acc[4] = {{0, 0, 0, 0}, {0, 0, 0, 0}, {0, 0, 0, 0}, {0, 0, 0, 0}};
#pragma unroll
    for (int kc = 0; kc < 8; ++kc) {
        bf16x8 a = bc8(areg[kc]);
#pragma unroll
        for (int ct = 0; ct < 4; ++ct) {
            bf16x8 bb = bc8(*(const u32x4*)(Bt + (ct * 16 + li) * 264 + kc * 32 + quad * 8));
            acc[ct] = MFMA16(a, bb, acc[ct]);
        }
    }

    int tensor = on >> 2, head = on & 3;
    if (tensor == 2) {
        // transpose tile through LDS (Bt reads all done after barrier), store vt[d][p]
        __syncthreads();
        u16* T = Bt;  // [64 d][72 p]
#pragma unroll
        for (int ct = 0; ct < 4; ++ct)
#pragma unroll
            for (int r = 0; r < 4; ++r)
                T[(ct * 16 + li) * 72 + wv * 16 + quad * 4 + r] = f2bf(acc[ct][r]);
        __syncthreads();
        int dr = t >> 2, pc = (t & 3) * 16;
        u32x4* g = (u32x4*)(vt + ((size_t)((b * 4 + head) * 64 + dr)) * 4096 + p0 + pc);
        const u32x4* s2 = (const u32x4*)(T + dr * 72 + pc);
        g[0] = s2[0];
        g[1] = s2[1];
    } else {
        u16* outp = (tensor == 0) ? q : k;
        float sc = (tensor == 0) ? QSCALE : 1.0f;
#pragma unroll
        for (int ct = 0; ct < 4; ++ct)
#pragma unroll
            for (int r = 0; r < 4; ++r) {
                int p = p0 + wv * 16 + quad * 4 + r;
                int d = ct * 16 + li;
                outp[((size_t)((b * 4 + head) * 4096 + p)) * 64 + d] = f2bf(acc[ct][r] * sc);
            }
    }
}

// ---------------------------------------------------------------------------
// K2b: bias tables via MFMA with rel_to_abs applied at store time.
__global__ __launch_bounds__(256) void k_rel(const u16* __restrict__ q,
                                             const u16* __restrict__ relwb,
                                             const u16* __restrict__ relhb,
                                             u16* __restrict__ Wabs, u16* __restrict__ Habs) {
    int pm = blockIdx.x, bh = blockIdx.y, z = blockIdx.z;
    int p0 = pm * 64;
    const u16* rel = z ? relhb : relwb;
    u16* outp = z ? Habs : Wabs;
    __shared__ __align__(16) u16 Ls[128 * 72];
    int t = threadIdx.x, wv = t >> 6, l = t & 63, quad = l >> 4, li = l & 15;

    {
        int row = t >> 1, half = t & 1;
        const u32x4* g = (const u32x4*)(rel + row * 64 + half * 32);
        u32x4* s = (u32x4*)(Ls + row * 72 + half * 32);
#pragma unroll
        for (int kk = 0; kk < 4; ++kk) s[kk] = g[kk];
    }

    u32x4 aq[2];
    const u32x4* qrow = (const u32x4*)(q + ((size_t)(bh * 4096 + p0 + wv * 16 + li)) * 64);
    aq[0] = qrow[quad];
    aq[1] = qrow[4 + quad];
    __syncthreads();

    f32x4 acc[8];
#pragma unroll
    for (int ct = 0; ct < 8; ++ct) acc[ct] = (f32x4){0.f, 0.f, 0.f, 0.f};
#pragma unroll
    for (int kc = 0; kc < 2; ++kc) {
        bf16x8 a = bc8(aq[kc]);
#pragma unroll
        for (int ct = 0; ct < 8; ++ct) {
            bf16x8 bb = bc8(*(const u32x4*)(Ls + (ct * 16 + li) * 72 + kc * 32 + quad * 8));
            acc[ct] = MFMA16(a, bb, acc[ct]);
        }
    }

#pragma unroll
    for (int ct = 0; ct < 8; ++ct)
#pragma unroll
        for (int r = 0; r < 4; ++r) {
            int row = wv * 16 + quad * 4 + r;
            int p = p0 + row;
            int c = ct * 16 + li;
            int shift = z ? pm : row;
            int j = c - 63 + shift;
            if (j >= 0 && j < 64)
                outp[((size_t)(bh * 4096 + p)) * 64 + j] = f2bf(acc[ct][r]);
        }
}

// ---------------------------------------------------------------------------
// K3: flash attention, v3. 4 waves x 32 q-rows = 128-row q-tile; K-split x2.
// Each wave owns 2 row-sets so every K/V B-frag LDS read is reused twice.
// Row-sum via constant ones-column appended to V (ct=4). Partials fp32 + combine.
__global__ __launch_bounds__(256, 2) void k_flash(const u16* __restrict__ q,
                                                  const u16* __restrict__ kg,
                                                  const u16* __restrict__ vt,
                                                  const u16* __restrict__ Wabs,
                                                  const u16* __restrict__ Habs,
                                                  float* __restrict__ OP,
                                                  float* __restrict__ LS) {
    int pm = blockIdx.x, bh = blockIdx.y, ks = blockIdx.z;
    int p0 = pm * 128;
    __shared__ __align__(16) u16 Kt[64 * 72];
    __shared__ __align__(16) u16 Vl[80 * 72];   // rows 64..79: ones-row + zeros
    __shared__ __align__(16) u16 Pl[4][32 * 72];
    __shared__ __align__(16) float Hl[128 * 36];
    int t = threadIdx.x, wv = t >> 6, l = t & 63, quad = l >> 4, li = l & 15;
    int rbase = wv * 32;

    // Q A-frags for both row-sets
    u32x4 aq[2][2];
#pragma unroll
    for (int rs = 0; rs < 2; ++rs) {
        const u32x4* qrow =
            (const u32x4*)(q + ((size_t)(bh * 4096 + p0 + rbase + rs * 16 + li)) * 64);
        aq[rs][0] = qrow[quad];
        aq[rs][1] = qrow[4 + quad];
    }

    // width-bias per C-frag element
    float wb[2][4][4];
#pragma unroll
    for (int rs = 0; rs < 2; ++rs)
#pragma unroll
        for (int ct = 0; ct < 4; ++ct)
#pragma unroll
            for (int r = 0; r < 4; ++r)
                wb[rs][ct][r] = bf2f(
                    Wabs[((size_t)(bh * 4096 + p0 + rbase + rs * 16 + quad * 4 + r)) * 64 +
                         ct * 16 + li]);

    // height-bias tile: 128 rows x 32 local kt cols
    {
        int row = t >> 1, ch = (t & 1) * 16;
        const u16* g = Habs + ((size_t)(bh * 4096 + p0 + row)) * 64 + ks * 32 + ch;
        float* dst = Hl + row * 36 + ch;
#pragma unroll
        for (int kk = 0; kk < 16; ++kk) dst[kk] = bf2f(g[kk]);
    }
    // constant V rows: row 64 = ones (lsum column), 65..79 = zeros
    for (int idx = t; idx < 16 * 72; idx += 256) {
        int rr = idx / 72, cc = idx - rr * 72;
        Vl[(64 + rr) * 72 + cc] = (rr == 0 && cc < 64) ? (u16)0x3F80 : (u16)0;
    }

    int srow = t >> 2, scc = (t & 3) * 16;
    u32x4 kreg[2], vreg[2];
    {
        int j0 = ks * 2048;
        const u32x4* gk = (const u32x4*)(kg + ((size_t)(bh * 4096 + j0 + srow)) * 64 + scc);
        kreg[0] = gk[0];
        kreg[1] = gk[1];
        const u32x4* gv = (const u32x4*)(vt + ((size_t)(bh * 64 + srow)) * 4096 + j0 + scc);
        vreg[0] = gv[0];
        vreg[1] = gv[1];
    }

    f32x4 oacc[2][5];
#pragma unroll
    for (int rs = 0; rs < 2; ++rs)
#pragma unroll
        for (int ct = 0; ct < 5; ++ct) oacc[rs][ct] = (f32x4){0.f, 0.f, 0.f, 0.f};

    for (int kt = 0; kt < 32; ++kt) {
        // commit prefetched tile to LDS
        {
            u32x4* sk = (u32x4*)(Kt + srow * 72 + scc);
            sk[0] = kreg[0];
            sk[1] = kreg[1];
            u32x4* sv = (u32x4*)(Vl + srow * 72 + scc);
            sv[0] = vreg[0];
            sv[1] = vreg[1];
        }
        __syncthreads();
        // prefetch next tile (overlaps compute below)
        if (kt < 31) {
            int j0 = (ks * 32 + kt + 1) * 64;
            const u32x4* gk = (const u32x4*)(kg + ((size_t)(bh * 4096 + j0 + srow)) * 64 + scc);
            kreg[0] = gk[0];
            kreg[1] = gk[1];
            const u32x4* gv = (const u32x4*)(vt + ((size_t)(bh * 64 + srow)) * 4096 + j0 + scc);
            vreg[0] = gv[0];
            vreg[1] = gv[1];
        }

        // S = Q K^T : 32x64 per wave, B-frags read once, used by both row-sets
        f32x4 s[2][4];
#pragma unroll
        for (int rs = 0; rs < 2; ++rs)
#pragma unroll
            for (int ct = 0; ct < 4; ++ct) s[rs][ct] = (f32x4){0.f, 0.f, 0.f, 0.f};
#pragma unroll
        for (int kc = 0; kc < 2; ++kc) {
            bf16x8 a0 = bc8(aq[0][kc]), a1 = bc8(aq[1][kc]);
#pragma unroll
            for (int ct = 0; ct < 4; ++ct) {
                bf16x8 bb = bc8(*(const u32x4*)(Kt + (ct * 16 + li) * 72 + kc * 32 + quad * 8));
                s[0][ct] = MFMA16(a0, bb, s[0][ct]);
                s[1][ct] = MFMA16(a1, bb, s[1][ct]);
            }
        }

        // bias + exp2 + write P (per-wave LDS region; same-wave in-order DS)
        u16* P = Pl[wv];
#pragma unroll
        for (int rs = 0; rs < 2; ++rs) {
            float hh[4];
#pragma unroll
            for (int r = 0; r < 4; ++r)
                hh[r] = Hl[(rbase + rs * 16 + quad * 4 + r) * 36 + kt];
#pragma unroll
            for (int ct = 0; ct < 4; ++ct)
#pragma unroll
                for (int r = 0; r < 4; ++r) {
                    float pe = EXP2F(s[rs][ct][r] + wb[rs][ct][r] + hh[r]);
                    u32 u = (__builtin_bit_cast(u32, pe) + 0x8000u) >> 16;
                    P[(rs * 16 + quad * 4 + r) * 72 + ct * 16 + li] = (u16)u;
                }
        }

        // O += P V  (ct=4 accumulates row sums via ones-column)
        u32x4 par[2][2];
#pragma unroll
        for (int rs = 0; rs < 2; ++rs)
#pragma unroll
            for (int kc = 0; kc < 2; ++kc)
                par[rs][kc] = *(const u32x4*)(P + (rs * 16 + li) * 72 + kc * 32 + quad * 8);
#pragma unroll
        for (int kc = 0; kc < 2; ++kc) {
            bf16x8 pf0 = bc8(par[0][kc]), pf1 = bc8(par[1][kc]);
#pragma unroll
            for (int ct = 0; ct < 5; ++ct) {
                bf16x8 bb = bc8(*(const u32x4*)(Vl + (ct * 16 + li) * 72 + kc * 32 + quad * 8));
                oacc[0][ct] = MFMA16(pf0, bb, oacc[0][ct]);
                oacc[1][ct] = MFMA16(pf1, bb, oacc[1][ct]);
            }
        }
        __syncthreads();
    }

    // store raw partials (normalization in combine)
#pragma unroll
    for (int rs = 0; rs < 2; ++rs) {
#pragma unroll
        for (int ct = 0; ct < 4; ++ct)
#pragma unroll
            for (int r = 0; r < 4; ++r) {
                int p = p0 + rbase + rs * 16 + quad * 4 + r;
                OP[((size_t)((ks * 8 + bh) * 4096 + p)) * 64 + ct * 16 + li] = oacc[rs][ct][r];
            }
        if (li == 0) {
#pragma unroll
            for (int r = 0; r < 4; ++r) {
                int p = p0 + rbase + rs * 16 + quad * 4 + r;
                LS[(size_t)(ks * 8 + bh) * 4096 + p] = oacc[rs][4][r];
            }
        }
    }
}

// ---------------------------------------------------------------------------
// K3b: combine K-split partials -> O bf16
__global__ __launch_bounds__(256) void k_comb(const float* __restrict__ OP,
                                              const float* __restrict__ LS,
                                              u16* __restrict__ O) {
    int idx = blockIdx.x * 256 + threadIdx.x;
    int d = idx & 63, p = (idx >> 6) & 4095, bh = idx >> 18;
    size_t i0 = (size_t)(bh * 4096 + p);
    size_t i1 = (size_t)((8 + bh) * 4096 + p);
    float lsum = LS[i0] + LS[i1];
    float o = OP[i0 * 64 + d] + OP[i1 * 64 + d];
    O[i0 * 64 + d] = f2bf(o / lsum);
}

// ---------------------------------------------------------------------------
// K4: out projection + residual. C[co,p] = sum_c wout[co,c] * O[b,p,c] ; += x
__global__ __launch_bounds__(256) void k_out(const u16* __restrict__ wob, const u16* __restrict__ O,
                                             const float* __restrict__ x, float* __restrict__ out) {
    int pm = blockIdx.x, com = blockIdx.y, b = blockIdx.z;
    int p0 = pm * 64, co0 = com * 64;
    __shared__ __align__(16) u16 Bt[64 * 264];
    int t = threadIdx.x, wv = t >> 6, l = t & 63, quad = l >> 4, li = l & 15;

    u32x4 areg[8];
    const u32x4* arow = (const u32x4*)(wob + (size_t)(co0 + wv * 16 + li) * 256);
#pragma unroll
    for (int kc = 0; kc < 8; ++kc) areg[kc] = arow[kc * 4 + quad];

    {
        int row = t >> 2, head = t & 3;
        const u32x4* g = (const u32x4*)(O + ((size_t)((b * 4 + head) * 4096 + p0 + row)) * 64);
        u32x4* s = (u32x4*)(Bt + row * 264 + head * 64);
#pragma unroll
        for (int kk = 0; kk < 8; ++kk) s[kk] = g[kk];
    }
    __syncthreads();

    f32x4 acc[4] = {{0, 0, 0, 0}, {0, 0, 0, 0}, {0, 0, 0, 0}, {0, 0, 0, 0}};
#pragma unroll
    for (int kc = 0; kc < 8; ++kc) {
        bf16x8 a = bc8(areg[kc]);
#pragma unroll
        for (int ct = 0; ct < 4; ++ct) {
            bf16x8 bb = bc8(*(const u32x4*)(Bt + (ct * 16 + li) * 264 + kc * 32 + quad * 8));
            acc[ct] = MFMA16(a, bb, acc[ct]);
        }
    }

#pragma unroll
    for (int ct = 0; ct < 4; ++ct)
#pragma unroll
        for (int r = 0; r < 4; ++r) {
            size_t idx = ((size_t)(b * 256 + co0 + wv * 16 + quad * 4 + r)) * 4096 + p0 + ct * 16 + li;
            out[idx] = acc[ct][r] + x[idx];
        }
}

// ---------------------------------------------------------------------------
extern "C" void kernel_launch(void* const* d_in, const int* in_sizes, int n_in, void* d_out,
                              int out_size, void* d_ws, size_t ws_size, hipStream_t stream) {
    const float* x = (const float*)d_in[0];
    const float* wqkv = (const float*)d_in[1];
    const float* wout = (const float*)d_in[2];
    const float* relh = (const float*)d_in[3];
    const float* relw = (const float*)d_in[4];
    float* out = (float*)d_out;
    char* ws = (char*)d_ws;

    u16* xt = (u16*)(ws + 0);               // 4,194,304 (dead after k_qkv; reused as Ob)
    u16* wqb = (u16*)(ws + 4194304);        //   393,216
    u16* wob = (u16*)(ws + 4587520);        //   131,072
    u16* relwb = (u16*)(ws + 4718592);      //    16,384
    u16* relhb = (u16*)(ws + 4734976);      //    16,384
    u16* qb = (u16*)(ws + 4751360);         // 4,194,304
    u16* kb = (u16*)(ws + 8945664);         // 4,194,304
    u16* vtb = (u16*)(ws + 13139968);       // 4,194,304
    u16* Wabs = (u16*)(ws + 17334272);      // 4,194,304
    u16* Habs = (u16*)(ws + 21528576);      // 4,194,304
    float* OPart = (float*)(ws + 25722880); // 16,777,216 (2 x 8 x 4096 x 64 fp32)
    float* LSum = (float*)(ws + 42500096);  //    262,144 (2 x 8 x 4096 fp32)  end ~40.8 MB
    u16* Ob = xt;                           // alias: xt dead before k_comb writes Ob

    k_cast_w<<<1024, 256, 0, stream>>>(wqkv, wout, relh, relw, wqb, wob, relhb, relwb);
    k_tx<<<dim3(64, 4, 2), 256, 0, stream>>>(x, xt);
    k_qkv<<<dim3(64, 12, 2), 256, 0, stream>>>(xt, wqb, qb, kb, vtb);
    k_rel<<<dim3(64, 8, 2), 256, 0, stream>>>(qb, relwb, relhb, Wabs, Habs);
    k_flash<<<dim3(32, 8, 2), 256, 0, stream>>>(qb, kb, vtb, Wabs, Habs, OPart, LSum);
    k_comb<<<8192, 256, 0, stream>>>(OPart, LSum, Ob);
    k_out<<<dim3(64, 4, 2), 256, 0, stream>>>(wob, Ob, x, out);
}

// Round 4
// 165.720 us; speedup vs baseline: 1.8292x; 1.0355x over previous
//
#include <hip/hip_runtime.h>

typedef unsigned short u16;
typedef unsigned int u32;
typedef __bf16 bf16x8 __attribute__((ext_vector_type(8)));
typedef float f32x4 __attribute__((ext_vector_type(4)));
typedef u32 u32x4 __attribute__((ext_vector_type(4)));
typedef u32 u32x2 __attribute__((ext_vector_type(2)));
typedef short s16x4 __attribute__((ext_vector_type(4)));

#define DEVI __device__ __forceinline__

#if defined(__has_builtin)
#if __has_builtin(__builtin_amdgcn_exp2f)
#define EXP2F(x) __builtin_amdgcn_exp2f(x)
#endif
#endif
#ifndef EXP2F
#define EXP2F(x) exp2f(x)
#endif

#define MFMA16(a, b, c) __builtin_amdgcn_mfma_f32_16x16x32_bf16(a, b, c, 0, 0, 0)
#define MFMA1K(a, b, c) __builtin_amdgcn_mfma_f32_16x16x16bf16_1k(a, b, c, 0, 0, 0)

DEVI u16 f2bf(float f) {
    u32 u = __builtin_bit_cast(u32, f);
    u = (u + 0x7FFFu + ((u >> 16) & 1u)) >> 16;
    return (u16)u;
}
DEVI float bf2f(u16 h) {
    u32 u = ((u32)h) << 16;
    return __builtin_bit_cast(float, u);
}
DEVI float bfhi(u32 u) { return __builtin_bit_cast(float, u & 0xFFFF0000u); }
DEVI float bflo(u32 u) { return __builtin_bit_cast(float, u << 16); }
DEVI bf16x8 bc8(u32x4 u) { return __builtin_bit_cast(bf16x8, u); }

// q scale: dh^-0.5 * log2(e)  (bakes natural-exp into exp2)
#define QSCALE 0.18033688011112042f

// ---------------------------------------------------------------------------
// K0: fused prep. Blocks [0,512): transpose+cast x -> xt[b][p][c] bf16.
//     Blocks [512,768): cast weights + rel tables (rel zero-padded to 128 rows).
__global__ __launch_bounds__(256) void k_prep(const float* __restrict__ x,
                                              const float* __restrict__ wq,
                                              const float* __restrict__ wo,
                                              const float* __restrict__ relh,
                                              const float* __restrict__ relw,
                                              u16* __restrict__ xt, u16* __restrict__ wqb,
                                              u16* __restrict__ wob, u16* __restrict__ relhb,
                                              u16* __restrict__ relwb) {
    int bid = blockIdx.x;
    int t = threadIdx.x;
    if (bid < 512) {
        int pm = bid & 63, cm = (bid >> 6) & 3, b = bid >> 8;
        int p0 = pm * 64, c0 = cm * 64;
        __shared__ float tile[64][65];
#pragma unroll
        for (int it = 0; it < 16; ++it) {
            int idx = it * 256 + t;
            int cl = idx >> 6, pl = idx & 63;
            tile[cl][pl] = x[((size_t)(b * 256 + c0 + cl)) * 4096 + p0 + pl];
        }
        __syncthreads();
#pragma unroll
        for (int it = 0; it < 16; ++it) {
            int idx = it * 256 + t;
            int pl = idx >> 6, cl = idx & 63;
            xt[((size_t)(b * 4096 + p0 + pl)) * 256 + c0 + cl] = f2bf(tile[cl][pl]);
        }
    } else {
        int i0 = (bid - 512) * 256 + t;  // 65536 stride
#pragma unroll
        for (int i = i0; i < 196608; i += 65536) wqb[i] = f2bf(wq[i]);
        if (i0 < 65536) wob[i0] = f2bf(wo[i0]);
        if (i0 < 8192) {
            relhb[i0] = (i0 < 8128) ? f2bf(relh[i0]) : (u16)0;
            relwb[i0] = (i0 < 8128) ? f2bf(relw[i0]) : (u16)0;
        }
    }
}

// ---------------------------------------------------------------------------
// K1: QKV projection GEMM. C[p,o] = sum_c xt[p,c] * wqkv[o,c]
// tensor==2 (v) blocks transpose through LDS and store vt[bh][d][p] directly.
__global__ __launch_bounds__(256) void k_qkv(const u16* __restrict__ xt, const u16* __restrict__ wqb,
                                             u16* __restrict__ q, u16* __restrict__ k,
                                             u16* __restrict__ vt) {
    int pm = blockIdx.x, on = blockIdx.y, b = blockIdx.z;
    int p0 = pm * 64, o0 = on * 64;
    __shared__ __align__(16) u16 Bt[64 * 264];
    int t = threadIdx.x;
    int wv = t >> 6, l = t & 63, quad = l >> 4, li = l & 15;

    u32x4 areg[8];
    const u32x4* arow = (const u32x4*)(xt + ((size_t)(b * 4096 + p0 + wv * 16 + li)) * 256);
#pragma unroll
    for (int kc = 0; kc < 8; ++kc) areg[kc] = arow[kc * 4 + quad];

    {
        int row = t >> 2, c0 = (t & 3) * 64;
        const u32x4* g = (const u32x4*)(wqb + (size_t)(o0 + row) * 256 + c0);
        u32x4* s = (u32x4*)(Bt + row * 264 + c0);
#pragma unroll
        for (int kk = 0; kk < 8; ++kk) s[kk] = g[kk];
    }
    __syncthreads();

    f32x4 acc[4] = {{0, 0, 0, 0}, {0, 0, 0, 0}, {0, 0, 0, 0}, {0, 0, 0, 0}};
#pragma unroll
    for (int kc = 0; kc < 8; ++kc) {
        bf16x8 a = bc8(areg[kc]);
#pragma unroll
        for (int ct = 0; ct < 4; ++ct) {
            bf16x8 bb = bc8(*(const u32x4*)(Bt + (ct * 16 + li) * 264 + kc * 32 + quad * 8));
            acc[ct] = MFMA16(a, bb, acc[ct]);
        }
    }

    int tensor = on >> 2, head = on & 3;
    if (tensor == 2) {
        __syncthreads();
        u16* T = Bt;  // [64 d][72 p]
#pragma unroll
        for (int ct = 0; ct < 4; ++ct)
#pragma unroll
            for (int r = 0; r < 4; ++r)
                T[(ct * 16 + li) * 72 + wv * 16 + quad * 4 + r] = f2bf(acc[ct][r]);
        __syncthreads();
        int dr = t >> 2, pc = (t & 3) * 16;
        u32x4* g = (u32x4*)(vt + ((size_t)((b * 4 + head) * 64 + dr)) * 4096 + p0 + pc);
        const u32x4* s2 = (const u32x4*)(T + dr * 72 + pc);
        g[0] = s2[0];
        g[1] = s2[1];
    } else {
        u16* outp = (tensor == 0) ? q : k;
        float sc = (tensor == 0) ? QSCALE : 1.0f;
#pragma unroll
        for (int ct = 0; ct < 4; ++ct)
#pragma unroll
            for (int r = 0; r < 4; ++r) {
                int p = p0 + wv * 16 + quad * 4 + r;
                int d = ct * 16 + li;
                outp[((size_t)((b * 4 + head) * 4096 + p)) * 64 + d] = f2bf(acc[ct][r] * sc);
            }
    }
}

// ---------------------------------------------------------------------------
// K2b: bias tables via MFMA with rel_to_abs applied at store time.
__global__ __launch_bounds__(256) void k_rel(const u16* __restrict__ q,
                                             const u16* __restrict__ relwb,
                                             const u16* __restrict__ relhb,
                                             u16* __restrict__ Wabs, u16* __restrict__ Habs) {
    int pm = blockIdx.x, bh = blockIdx.y, z = blockIdx.z;
    int p0 = pm * 64;
    const u16* rel = z ? relhb : relwb;
    u16* outp = z ? Habs : Wabs;
    __shared__ __align__(16) u16 Ls[128 * 72];
    int t = threadIdx.x, wv = t >> 6, l = t & 63, quad = l >> 4, li = l & 15;

    {
        int row = t >> 1, half = t & 1;
        const u32x4* g = (const u32x4*)(rel + row * 64 + half * 32);
        u32x4* s = (u32x4*)(Ls + row * 72 + half * 32);
#pragma unroll
        for (int kk = 0; kk < 4; ++kk) s[kk] = g[kk];
    }

    u32x4 aq[2];
    const u32x4* qrow = (const u32x4*)(q + ((size_t)(bh * 4096 + p0 + wv * 16 + li)) * 64);
    aq[0] = qrow[quad];
    aq[1] = qrow[4 + quad];
    __syncthreads();

    f32x4 acc[8];
#pragma unroll
    for (int ct = 0; ct < 8; ++ct) acc[ct] = (f32x4){0.f, 0.f, 0.f, 0.f};
#pragma unroll
    for (int kc = 0; kc < 2; ++kc) {
        bf16x8 a = bc8(aq[kc]);
#pragma unroll
        for (int ct = 0; ct < 8; ++ct) {
            bf16x8 bb = bc8(*(const u32x4*)(Ls + (ct * 16 + li) * 72 + kc * 32 + quad * 8));
            acc[ct] = MFMA16(a, bb, acc[ct]);
        }
    }

#pragma unroll
    for (int ct = 0; ct < 8; ++ct)
#pragma unroll
        for (int r = 0; r < 4; ++r) {
            int row = wv * 16 + quad * 4 + r;
            int p = p0 + row;
            int c = ct * 16 + li;
            int shift = z ? pm : row;
            int j = c - 63 + shift;
            if (j >= 0 && j < 64)
                outp[((size_t)(bh * 4096 + p)) * 64 + j] = f2bf(acc[ct][r]);
        }
}

// ---------------------------------------------------------------------------
// K3: flash attention v4 — P never touches LDS.
// S^T = MFMA16x16x32(A=K-frag from LDS, B=Q-frag registers): C-frag at (lane,reg)
// holds P[qrow=lane&15][j=quad*4+reg], which IS the 16x16x16 A-layout of P.
// So O = MFMA1K(A=exp(S^T)-frag, B=V^T-frag ds_read_b64) accumulates in regs.
// Row-sum via ones B-tile (dt=4). K-split x2, fp32 partials.
__global__ __launch_bounds__(256, 2) void k_flash(const u16* __restrict__ q,
                                                  const u16* __restrict__ kg,
                                                  const u16* __restrict__ vt,
                                                  const u16* __restrict__ Wabs,
                                                  const u16* __restrict__ Habs,
                                                  float* __restrict__ OP,
                                                  float* __restrict__ LS) {
    int pm = blockIdx.x, bh = blockIdx.y, ks = blockIdx.z;
    int p0 = pm * 128;
    __shared__ __align__(16) u16 Kt[64 * 72];
    __shared__ __align__(16) u16 Vl[64 * 72];
    __shared__ __align__(16) u16 Hl[128 * 40];
    int t = threadIdx.x, wv = t >> 6, l = t & 63, quad = l >> 4, li = l & 15;
    int rbase = wv * 32;

    // Q B-frags (B[k=d][n=qrow]; per-lane data identical to the old A-frag load)
    u32x4 aq[2][2];
#pragma unroll
    for (int rs = 0; rs < 2; ++rs) {
        const u32x4* qrow =
            (const u32x4*)(q + ((size_t)(bh * 4096 + p0 + rbase + rs * 16 + li)) * 64);
        aq[rs][0] = qrow[quad];
        aq[rs][1] = qrow[4 + quad];
    }

    // width-bias, aligned to the S^T C-frag: element (rs,ct,r) = Wabs[qrow][ct*16+quad*4+r]
    float wbf[2][4][4];
#pragma unroll
    for (int rs = 0; rs < 2; ++rs)
#pragma unroll
        for (int ct = 0; ct < 4; ++ct) {
            const u32* wp = (const u32*)(Wabs +
                                         ((size_t)(bh * 4096 + p0 + rbase + rs * 16 + li)) * 64 +
                                         ct * 16 + quad * 4);
            u32 lo = wp[0], hi = wp[1];
            wbf[rs][ct][0] = bflo(lo);
            wbf[rs][ct][1] = bfhi(lo);
            wbf[rs][ct][2] = bflo(hi);
            wbf[rs][ct][3] = bfhi(hi);
        }

    // height-bias tile: 128 rows x 32 local kt cols, bf16 in LDS (stride 40)
    {
        int row = t >> 1, ch = (t & 1) * 16;
        const u32x4* g = (const u32x4*)(Habs + ((size_t)(bh * 4096 + p0 + row)) * 64 + ks * 32 + ch);
        u32x4* d = (u32x4*)(Hl + row * 40 + ch);
        d[0] = g[0];
        d[1] = g[1];
    }

    int srow = t >> 2, scc = (t & 3) * 16;
    u32x4 kreg[2], vreg[2];
    {
        int j0 = ks * 2048;
        const u32x4* gk = (const u32x4*)(kg + ((size_t)(bh * 4096 + j0 + srow)) * 64 + scc);
        kreg[0] = gk[0];
        kreg[1] = gk[1];
        const u32x4* gv = (const u32x4*)(vt + ((size_t)(bh * 64 + srow)) * 4096 + j0 + scc);
        vreg[0] = gv[0];
        vreg[1] = gv[1];
    }

    f32x4 oacc[2][5];
#pragma unroll
    for (int rs = 0; rs < 2; ++rs)
#pragma unroll
        for (int ct = 0; ct < 5; ++ct) oacc[rs][ct] = (f32x4){0.f, 0.f, 0.f, 0.f};

    const s16x4 ones = {(short)0x3F80, (short)0x3F80, (short)0x3F80, (short)0x3F80};

    for (int kt = 0; kt < 32; ++kt) {
        {
            u32x4* sk = (u32x4*)(Kt + srow * 72 + scc);
            sk[0] = kreg[0];
            sk[1] = kreg[1];
            u32x4* sv = (u32x4*)(Vl + srow * 72 + scc);
            sv[0] = vreg[0];
            sv[1] = vreg[1];
        }
        __syncthreads();
        if (kt < 31) {
            int j0 = (ks * 32 + kt + 1) * 64;
            const u32x4* gk = (const u32x4*)(kg + ((size_t)(bh * 4096 + j0 + srow)) * 64 + scc);
            kreg[0] = gk[0];
            kreg[1] = gk[1];
            const u32x4* gv = (const u32x4*)(vt + ((size_t)(bh * 64 + srow)) * 4096 + j0 + scc);
            vreg[0] = gv[0];
            vreg[1] = gv[1];
        }

        // S^T = K · Q^T : per wave 64j x 32qrow, K-frags read once for both rs
        f32x4 s[2][4];
#pragma unroll
        for (int rs = 0; rs < 2; ++rs)
#pragma unroll
            for (int ct = 0; ct < 4; ++ct) s[rs][ct] = (f32x4){0.f, 0.f, 0.f, 0.f};
#pragma unroll
        for (int kc = 0; kc < 2; ++kc) {
            bf16x8 b0 = bc8(aq[0][kc]), b1 = bc8(aq[1][kc]);
#pragma unroll
            for (int ct = 0; ct < 4; ++ct) {
                bf16x8 af = bc8(*(const u32x4*)(Kt + (ct * 16 + li) * 72 + kc * 32 + quad * 8));
                s[0][ct] = MFMA16(af, b0, s[0][ct]);
                s[1][ct] = MFMA16(af, b1, s[1][ct]);
            }
        }

        // bias + exp2 + pack to bf16 P-fragments (registers only)
        s16x4 pf[2][4];
#pragma unroll
        for (int rs = 0; rs < 2; ++rs) {
            float hh = bf2f(Hl[(rbase + rs * 16 + li) * 40 + kt]);
#pragma unroll
            for (int ct = 0; ct < 4; ++ct) {
                u32 e0 = __builtin_bit_cast(u32, EXP2F(s[rs][ct][0] + wbf[rs][ct][0] + hh));
                u32 e1 = __builtin_bit_cast(u32, EXP2F(s[rs][ct][1] + wbf[rs][ct][1] + hh));
                u32 e2 = __builtin_bit_cast(u32, EXP2F(s[rs][ct][2] + wbf[rs][ct][2] + hh));
                u32 e3 = __builtin_bit_cast(u32, EXP2F(s[rs][ct][3] + wbf[rs][ct][3] + hh));
                u32x2 pp;
                pp.x = ((e0 + 0x8000u) >> 16) | ((e1 + 0x8000u) & 0xFFFF0000u);
                pp.y = ((e2 + 0x8000u) >> 16) | ((e3 + 0x8000u) & 0xFFFF0000u);
                pf[rs][ct] = __builtin_bit_cast(s16x4, pp);
            }
        }

        // O += P · V : B-frags from V^T (ds_read_b64), shared across rs; dt=4 = ones (lsum)
#pragma unroll
        for (int jt = 0; jt < 4; ++jt) {
            s16x4 a0 = pf[0][jt], a1 = pf[1][jt];
#pragma unroll
            for (int dt = 0; dt < 4; ++dt) {
                s16x4 bv = __builtin_bit_cast(
                    s16x4, *(const u32x2*)(Vl + (dt * 16 + li) * 72 + jt * 16 + quad * 4));
                oacc[0][dt] = MFMA1K(a0, bv, oacc[0][dt]);
                oacc[1][dt] = MFMA1K(a1, bv, oacc[1][dt]);
            }
            oacc[0][4] = MFMA1K(a0, ones, oacc[0][4]);
            oacc[1][4] = MFMA1K(a1, ones, oacc[1][4]);
        }
        __syncthreads();
    }

    // store raw partials (normalization in k_out2)
#pragma unroll
    for (int rs = 0; rs < 2; ++rs) {
#pragma unroll
        for (int ct = 0; ct < 4; ++ct)
#pragma unroll
            for (int r = 0; r < 4; ++r) {
                int p = p0 + rbase + rs * 16 + quad * 4 + r;
                OP[((size_t)((ks * 8 + bh) * 4096 + p)) * 64 + ct * 16 + li] = oacc[rs][ct][r];
            }
        if (li == 0) {
#pragma unroll
            for (int r = 0; r < 4; ++r) {
                int p = p0 + rbase + rs * 16 + quad * 4 + r;
                LS[(size_t)(ks * 8 + bh) * 4096 + p] = oacc[rs][4][r];
            }
        }
    }
}

// ---------------------------------------------------------------------------
// K4: fused combine + out-projection + residual.
// Stage combined O tile [64p][256c] once (from fp32 partials, normalized),
// then loop the 4 co-tiles of the projection. grid (64 pm, 2 b), 256 thr.
__global__ __launch_bounds__(256) void k_out2(const u16* __restrict__ wob,
                                              const float* __restrict__ OP,
                                              const float* __restrict__ LS,
                                              const float* __restrict__ x,
                                              float* __restrict__ out) {
    int pm = blockIdx.x, b = blockIdx.y;
    int p0 = pm * 64;
    __shared__ __align__(16) u16 Bt[64 * 264];
    int t = threadIdx.x, wv = t >> 6, l = t & 63, quad = l >> 4, li = l & 15;

    {
        int row = t >> 2, head = t & 3;
        int bh = b * 4 + head;
        int p = p0 + row;
        const f32x4* o0p = (const f32x4*)(OP + ((size_t)(bh * 4096 + p)) * 64);
        const f32x4* o1p = (const f32x4*)(OP + ((size_t)((8 + bh) * 4096 + p)) * 64);
        float linv = 1.0f / (LS[(size_t)bh * 4096 + p] + LS[(size_t)(8 + bh) * 4096 + p]);
        u16* dst = Bt + row * 264 + head * 64;
#pragma unroll
        for (int kk = 0; kk < 8; ++kk) {
            f32x4 a = o0p[2 * kk], c = o1p[2 * kk];
            f32x4 a2 = o0p[2 * kk + 1], c2 = o1p[2 * kk + 1];
            u32x4 pk;
            u32 u0 = __builtin_bit_cast(u32, (a[0] + c[0]) * linv);
            u32 u1 = __builtin_bit_cast(u32, (a[1] + c[1]) * linv);
            u32 u2 = __builtin_bit_cast(u32, (a[2] + c[2]) * linv);
            u32 u3 = __builtin_bit_cast(u32, (a[3] + c[3]) * linv);
            u32 u4 = __builtin_bit_cast(u32, (a2[0] + c2[0]) * linv);
            u32 u5 = __builtin_bit_cast(u32, (a2[1] + c2[1]) * linv);
            u32 u6 = __builtin_bit_cast(u32, (a2[2] + c2[2]) * linv);
            u32 u7 = __builtin_bit_cast(u32, (a2[3] + c2[3]) * linv);
            pk.x = ((u0 + 0x8000u) >> 16) | ((u1 + 0x8000u) & 0xFFFF0000u);
            pk.y = ((u2 + 0x8000u) >> 16) | ((u3 + 0x8000u) & 0xFFFF0000u);
            pk.z = ((u4 + 0x8000u) >> 16) | ((u5 + 0x8000u) & 0xFFFF0000u);
            pk.w = ((u6 + 0x8000u) >> 16) | ((u7 + 0x8000u) & 0xFFFF0000u);
            *(u32x4*)(dst + kk * 8) = pk;
        }
    }
    __syncthreads();

    for (int com = 0; com < 4; ++com) {
        int co0 = com * 64;
        f32x4 acc[4] = {{0, 0, 0, 0}, {0, 0, 0, 0}, {0, 0, 0, 0}, {0, 0, 0, 0}};
        const u32x4* arow = (const u32x4*)(wob + (size_t)(co0 + wv * 16 + li) * 256);
#pragma unroll
        for (int kc = 0; kc < 8; ++kc) {
            bf16x8 a = bc8(arow[kc * 4 + quad]);
#pragma unroll
            for (int ct = 0; ct < 4; ++ct) {
                bf16x8 bb = bc8(*(const u32x4*)(Bt + (ct * 16 + li) * 264 + kc * 32 + quad * 8));
                acc[ct] = MFMA16(a, bb, acc[ct]);
            }
        }
#pragma unroll
        for (int ct = 0; ct < 4; ++ct)
#pragma unroll
            for (int r = 0; r < 4; ++r) {
                size_t idx =
                    ((size_t)(b * 256 + co0 + wv * 16 + quad * 4 + r)) * 4096 + p0 + ct * 16 + li;
                out[idx] = acc[ct][r] + x[idx];
            }
    }
}

// ---------------------------------------------------------------------------
extern "C" void kernel_launch(void* const* d_in, const int* in_sizes, int n_in, void* d_out,
                              int out_size, void* d_ws, size_t ws_size, hipStream_t stream) {
    const float* x = (const float*)d_in[0];
    const float* wqkv = (const float*)d_in[1];
    const float* wout = (const float*)d_in[2];
    const float* relh = (const float*)d_in[3];
    const float* relw = (const float*)d_in[4];
    float* out = (float*)d_out;
    char* ws = (char*)d_ws;

    u16* xt = (u16*)(ws + 0);               // 4,194,304
    u16* wqb = (u16*)(ws + 4194304);        //   393,216
    u16* wob = (u16*)(ws + 4587520);        //   131,072
    u16* relwb = (u16*)(ws + 4718592);      //    16,384
    u16* relhb = (u16*)(ws + 4734976);      //    16,384
    u16* qb = (u16*)(ws + 4751360);         // 4,194,304
    u16* kb = (u16*)(ws + 8945664);         // 4,194,304
    u16* vtb = (u16*)(ws + 13139968);       // 4,194,304
    u16* Wabs = (u16*)(ws + 17334272);      // 4,194,304
    u16* Habs = (u16*)(ws + 21528576);      // 4,194,304
    float* OPart = (float*)(ws + 25722880); // 16,777,216 (2 x 8 x 4096 x 64 fp32)
    float* LSum = (float*)(ws + 42500096);  //    262,144  end ~42.8 MB

    k_prep<<<768, 256, 0, stream>>>(x, wqkv, wout, relh, relw, xt, wqb, wob, relhb, relwb);
    k_qkv<<<dim3(64, 12, 2), 256, 0, stream>>>(xt, wqb, qb, kb, vtb);
    k_rel<<<dim3(64, 8, 2), 256, 0, stream>>>(qb, relwb, relhb, Wabs, Habs);
    k_flash<<<dim3(32, 8, 2), 256, 0, stream>>>(qb, kb, vtb, Wabs, Habs, OPart, LSum);
    k_out2<<<dim3(64, 2), 256, 0, stream>>>(wob, OPart, LSum, x, out);
}

// Round 6
// 152.623 us; speedup vs baseline: 1.9861x; 1.0858x over previous
//
#include <hip/hip_runtime.h>

typedef unsigned short u16;
typedef unsigned int u32;
typedef __bf16 bf16x8 __attribute__((ext_vector_type(8)));
typedef __bf16 bf16x2 __attribute__((ext_vector_type(2)));
typedef float f32x4 __attribute__((ext_vector_type(4)));
typedef float f32x2 __attribute__((ext_vector_type(2)));
typedef u32 u32x4 __attribute__((ext_vector_type(4)));
typedef u32 u32x2 __attribute__((ext_vector_type(2)));
typedef short s16x4 __attribute__((ext_vector_type(4)));

#define DEVI __device__ __forceinline__

#if defined(__has_builtin)
#if __has_builtin(__builtin_amdgcn_exp2f)
#define EXP2F(x) __builtin_amdgcn_exp2f(x)
#endif
#endif
#ifndef EXP2F
#define EXP2F(x) exp2f(x)
#endif

#define MFMA16(a, b, c) __builtin_amdgcn_mfma_f32_16x16x32_bf16(a, b, c, 0, 0, 0)
#define MFMA1K(a, b, c) __builtin_amdgcn_mfma_f32_16x16x16bf16_1k(a, b, c, 0, 0, 0)

DEVI u16 f2bf(float f) {
    u32 u = __builtin_bit_cast(u32, f);
    u = (u + 0x7FFFu + ((u >> 16) & 1u)) >> 16;
    return (u16)u;
}
DEVI float bf2f(u16 h) {
    u32 u = ((u32)h) << 16;
    return __builtin_bit_cast(float, u);
}
DEVI float bfhi(u32 u) { return __builtin_bit_cast(float, u & 0xFFFF0000u); }
DEVI float bflo(u32 u) { return __builtin_bit_cast(float, u << 16); }
DEVI bf16x8 bc8(u32x4 u) { return __builtin_bit_cast(bf16x8, u); }
// pack two f32 -> packed bf16x2 (RNE; lowers to v_cvt_pk_bf16_f32 on gfx950)
DEVI u32 pack2(float a, float b) {
    f32x2 v = {a, b};
    bf16x2 h = __builtin_convertvector(v, bf16x2);
    return __builtin_bit_cast(u32, h);
}

// q scale: dh^-0.5 * log2(e)  (bakes natural-exp into exp2)
#define QSCALE 0.18033688011112042f

// ---------------------------------------------------------------------------
// K0: fused prep. Blocks [0,512): transpose+cast x -> xt[b][p][c] bf16.
//     Blocks [512,768): cast weights + rel tables (rel zero-padded to 128 rows).
__global__ __launch_bounds__(256) void k_prep(const float* __restrict__ x,
                                              const float* __restrict__ wq,
                                              const float* __restrict__ wo,
                                              const float* __restrict__ relh,
                                              const float* __restrict__ relw,
                                              u16* __restrict__ xt, u16* __restrict__ wqb,
                                              u16* __restrict__ wob, u16* __restrict__ relhb,
                                              u16* __restrict__ relwb) {
    int bid = blockIdx.x;
    int t = threadIdx.x;
    if (bid < 512) {
        int pm = bid & 63, cm = (bid >> 6) & 3, b = bid >> 8;
        int p0 = pm * 64, c0 = cm * 64;
        __shared__ float tile[64][65];
#pragma unroll
        for (int it = 0; it < 16; ++it) {
            int idx = it * 256 + t;
            int cl = idx >> 6, pl = idx & 63;
            tile[cl][pl] = x[((size_t)(b * 256 + c0 + cl)) * 4096 + p0 + pl];
        }
        __syncthreads();
#pragma unroll
        for (int it = 0; it < 16; ++it) {
            int idx = it * 256 + t;
            int pl = idx >> 6, cl = idx & 63;
            xt[((size_t)(b * 4096 + p0 + pl)) * 256 + c0 + cl] = f2bf(tile[cl][pl]);
        }
    } else {
        int i0 = (bid - 512) * 256 + t;  // 65536 stride
#pragma unroll
        for (int i = i0; i < 196608; i += 65536) wqb[i] = f2bf(wq[i]);
        if (i0 < 65536) wob[i0] = f2bf(wo[i0]);
        if (i0 < 8192) {
            relhb[i0] = (i0 < 8128) ? f2bf(relh[i0]) : (u16)0;
            relwb[i0] = (i0 < 8128) ? f2bf(relw[i0]) : (u16)0;
        }
    }
}

// ---------------------------------------------------------------------------
// K1: QKV projection GEMM. C[p,o] = sum_c xt[p,c] * wqkv[o,c]
// tensor==2 (v) blocks transpose through LDS and store vt[bh][d][p] directly.
__global__ __launch_bounds__(256) void k_qkv(const u16* __restrict__ xt, const u16* __restrict__ wqb,
                                             u16* __restrict__ q, u16* __restrict__ k,
                                             u16* __restrict__ vt) {
    int pm = blockIdx.x, on = blockIdx.y, b = blockIdx.z;
    int p0 = pm * 64, o0 = on * 64;
    __shared__ __align__(16) u16 Bt[64 * 264];
    int t = threadIdx.x;
    int wv = t >> 6, l = t & 63, quad = l >> 4, li = l & 15;

    u32x4 areg[8];
    const u32x4* arow = (const u32x4*)(xt + ((size_t)(b * 4096 + p0 + wv * 16 + li)) * 256);
#pragma unroll
    for (int kc = 0; kc < 8; ++kc) areg[kc] = arow[kc * 4 + quad];

    {
        int row = t >> 2, c0 = (t & 3) * 64;
        const u32x4* g = (const u32x4*)(wqb + (size_t)(o0 + row) * 256 + c0);
        u32x4* s = (u32x4*)(Bt + row * 264 + c0);
#pragma unroll
        for (int kk = 0; kk < 8; ++kk) s[kk] = g[kk];
    }
    __syncthreads();

    f32x4 acc[4] = {{0, 0, 0, 0}, {0, 0, 0, 0}, {0, 0, 0, 0}, {0, 0, 0, 0}};
#pragma unroll
    for (int kc = 0; kc < 8; ++kc) {
        bf16x8 a = bc8(areg[kc]);
#pragma unroll
        for (int ct = 0; ct < 4; ++ct) {
            bf16x8 bb = bc8(*(const u32x4*)(Bt + (ct * 16 + li) * 264 + kc * 32 + quad * 8));
            acc[ct] = MFMA16(a, bb, acc[ct]);
        }
    }

    int tensor = on >> 2, head = on & 3;
    if (tensor == 2) {
        __syncthreads();
        u16* T = Bt;  // [64 d][72 p]
#pragma unroll
        for (int ct = 0; ct < 4; ++ct)
#pragma unroll
            for (int r = 0; r < 4; ++r)
                T[(ct * 16 + li) * 72 + wv * 16 + quad * 4 + r] = f2bf(acc[ct][r]);
        __syncthreads();
        int dr = t >> 2, pc = (t & 3) * 16;
        u32x4* g = (u32x4*)(vt + ((size_t)((b * 4 + head) * 64 + dr)) * 4096 + p0 + pc);
        const u32x4* s2 = (const u32x4*)(T + dr * 72 + pc);
        g[0] = s2[0];
        g[1] = s2[1];
    } else {
        u16* outp = (tensor == 0) ? q : k;
        float sc = (tensor == 0) ? QSCALE : 1.0f;
#pragma unroll
        for (int ct = 0; ct < 4; ++ct)
#pragma unroll
            for (int r = 0; r < 4; ++r) {
                int p = p0 + wv * 16 + quad * 4 + r;
                int d = ct * 16 + li;
                outp[((size_t)((b * 4 + head) * 4096 + p)) * 64 + d] = f2bf(acc[ct][r] * sc);
            }
    }
}

// ---------------------------------------------------------------------------
// K2b: bias tables via MFMA with rel_to_abs applied at store time.
__global__ __launch_bounds__(256) void k_rel(const u16* __restrict__ q,
                                             const u16* __restrict__ relwb,
                                             const u16* __restrict__ relhb,
                                             u16* __restrict__ Wabs, u16* __restrict__ Habs) {
    int pm = blockIdx.x, bh = blockIdx.y, z = blockIdx.z;
    int p0 = pm * 64;
    const u16* rel = z ? relhb : relwb;
    u16* outp = z ? Habs : Wabs;
    __shared__ __align__(16) u16 Ls[128 * 72];
    int t = threadIdx.x, wv = t >> 6, l = t & 63, quad = l >> 4, li = l & 15;

    {
        int row = t >> 1, half = t & 1;
        const u32x4* g = (const u32x4*)(rel + row * 64 + half * 32);
        u32x4* s = (u32x4*)(Ls + row * 72 + half * 32);
#pragma unroll
        for (int kk = 0; kk < 4; ++kk) s[kk] = g[kk];
    }

    u32x4 aq[2];
    const u32x4* qrow = (const u32x4*)(q + ((size_t)(bh * 4096 + p0 + wv * 16 + li)) * 64);
    aq[0] = qrow[quad];
    aq[1] = qrow[4 + quad];
    __syncthreads();

    f32x4 acc[8];
#pragma unroll
    for (int ct = 0; ct < 8; ++ct) acc[ct] = (f32x4){0.f, 0.f, 0.f, 0.f};
#pragma unroll
    for (int kc = 0; kc < 2; ++kc) {
        bf16x8 a = bc8(aq[kc]);
#pragma unroll
        for (int ct = 0; ct < 8; ++ct) {
            bf16x8 bb = bc8(*(const u32x4*)(Ls + (ct * 16 + li) * 72 + kc * 32 + quad * 8));
            acc[ct] = MFMA16(a, bb, acc[ct]);
        }
    }

#pragma unroll
    for (int ct = 0; ct < 8; ++ct)
#pragma unroll
        for (int r = 0; r < 4; ++r) {
            int row = wv * 16 + quad * 4 + r;
            int p = p0 + row;
            int c = ct * 16 + li;
            int shift = z ? pm : row;
            int j = c - 63 + shift;
            if (j >= 0 && j < 64)
                outp[((size_t)(bh * 4096 + p)) * 64 + j] = f2bf(acc[ct][r]);
        }
}

// ---------------------------------------------------------------------------
// K3: flash attention v5 (fixed).
//  - biases folded into MFMA C-init: s[ct] starts at wb4[ct] + hh
//  - P packed with v_cvt_pk_bf16_f32, stays in registers (S^T->A-frag identity)
//  - double-buffered K/V LDS: ONE barrier per K-iter
//  - row-sum via ones B-operand (dt=4); bf16 partials + fp32 sums, K-split x2
__global__ __launch_bounds__(256, 2) void k_flash(const u16* __restrict__ q,
                                                  const u16* __restrict__ kg,
                                                  const u16* __restrict__ vt,
                                                  const u16* __restrict__ Wabs,
                                                  const u16* __restrict__ Habs,
                                                  u16* __restrict__ OP,
                                                  float* __restrict__ LS) {
    int pm = blockIdx.x, bh = blockIdx.y, ks = blockIdx.z;
    int p0 = pm * 128;
    __shared__ __align__(16) u16 Kt[2][64 * 72];
    __shared__ __align__(16) u16 Vl[2][64 * 72];
    __shared__ __align__(16) u16 Hl[128 * 40];
    int t = threadIdx.x, wv = t >> 6, l = t & 63, quad = l >> 4, li = l & 15;
    int rbase = wv * 32;

    // Q B-frags for both row-sets
    u32x4 aq[2][2];
#pragma unroll
    for (int rs = 0; rs < 2; ++rs) {
        const u32x4* qrow =
            (const u32x4*)(q + ((size_t)(bh * 4096 + p0 + rbase + rs * 16 + li)) * 64);
        aq[rs][0] = qrow[quad];
        aq[rs][1] = qrow[4 + quad];
    }

    // width-bias as f32x4 per (rs,ct), aligned to the S^T C-frag
    f32x4 wb4[2][4];
#pragma unroll
    for (int rs = 0; rs < 2; ++rs)
#pragma unroll
        for (int ct = 0; ct < 4; ++ct) {
            const u32* wp = (const u32*)(Wabs +
                                         ((size_t)(bh * 4096 + p0 + rbase + rs * 16 + li)) * 64 +
                                         ct * 16 + quad * 4);
            u32 lo = wp[0], hi = wp[1];
            wb4[rs][ct] = (f32x4){bflo(lo), bfhi(lo), bflo(hi), bfhi(hi)};
        }

    // height-bias tile: 128 rows x 32 local kt cols, bf16 in LDS (stride 40)
    {
        int row = t >> 1, ch = (t & 1) * 16;
        const u32x4* g = (const u32x4*)(Habs + ((size_t)(bh * 4096 + p0 + row)) * 64 + ks * 32 + ch);
        u32x4* d = (u32x4*)(Hl + row * 40 + ch);
        d[0] = g[0];
        d[1] = g[1];
    }

    int srow = t >> 2, scc = (t & 3) * 16;
    // preload tile 0 and commit to buffer 0
    {
        int j0 = ks * 2048;
        const u32x4* gk = (const u32x4*)(kg + ((size_t)(bh * 4096 + j0 + srow)) * 64 + scc);
        u32x4* sk = (u32x4*)(Kt[0] + srow * 72 + scc);
        sk[0] = gk[0];
        sk[1] = gk[1];
        const u32x4* gv = (const u32x4*)(vt + ((size_t)(bh * 64 + srow)) * 4096 + j0 + scc);
        u32x4* sv = (u32x4*)(Vl[0] + srow * 72 + scc);
        sv[0] = gv[0];
        sv[1] = gv[1];
    }

    f32x4 oacc[2][5];
#pragma unroll
    for (int rs = 0; rs < 2; ++rs)
#pragma unroll
        for (int ct = 0; ct < 5; ++ct) oacc[rs][ct] = (f32x4){0.f, 0.f, 0.f, 0.f};

    const s16x4 ones = {(short)0x3F80, (short)0x3F80, (short)0x3F80, (short)0x3F80};

    u32x4 kreg[2], vreg[2];
    for (int kt = 0; kt < 32; ++kt) {
        __syncthreads();  // tile kt ready in buf[kt&1]; prior reads of buf[(kt+1)&1] done
        int cur = kt & 1;
        const u16* Kc = Kt[cur];
        const u16* Vc = Vl[cur];
        if (kt < 31) {
            int j0 = (ks * 32 + kt + 1) * 64;
            const u32x4* gk = (const u32x4*)(kg + ((size_t)(bh * 4096 + j0 + srow)) * 64 + scc);
            kreg[0] = gk[0];
            kreg[1] = gk[1];
            const u32x4* gv = (const u32x4*)(vt + ((size_t)(bh * 64 + srow)) * 4096 + j0 + scc);
            vreg[0] = gv[0];
            vreg[1] = gv[1];
        }

        // S^T = K · Q^T with bias-initialized accumulators
        float hh0 = bf2f(Hl[(rbase + li) * 40 + kt]);
        float hh1 = bf2f(Hl[(rbase + 16 + li) * 40 + kt]);
        f32x4 s[2][4];
#pragma unroll
        for (int ct = 0; ct < 4; ++ct) {
            s[0][ct] = wb4[0][ct] + hh0;
            s[1][ct] = wb4[1][ct] + hh1;
        }
#pragma unroll
        for (int kc = 0; kc < 2; ++kc) {
            bf16x8 b0 = bc8(aq[0][kc]), b1 = bc8(aq[1][kc]);
#pragma unroll
            for (int ct = 0; ct < 4; ++ct) {
                bf16x8 af = bc8(*(const u32x4*)(Kc + (ct * 16 + li) * 72 + kc * 32 + quad * 8));
                s[0][ct] = MFMA16(af, b0, s[0][ct]);
                s[1][ct] = MFMA16(af, b1, s[1][ct]);
            }
        }

        // exp2 + packed bf16 P-fragments (registers only)
        s16x4 pf[2][4];
#pragma unroll
        for (int rs = 0; rs < 2; ++rs)
#pragma unroll
            for (int ct = 0; ct < 4; ++ct) {
                u32x2 pp;
                pp.x = pack2(EXP2F(s[rs][ct][0]), EXP2F(s[rs][ct][1]));
                pp.y = pack2(EXP2F(s[rs][ct][2]), EXP2F(s[rs][ct][3]));
                pf[rs][ct] = __builtin_bit_cast(s16x4, pp);
            }

        // O += P · V ; dt=4 accumulates row sums via ones operand
#pragma unroll
        for (int jt = 0; jt < 4; ++jt) {
            s16x4 a0 = pf[0][jt], a1 = pf[1][jt];
#pragma unroll
            for (int dt = 0; dt < 4; ++dt) {
                s16x4 bv = __builtin_bit_cast(
                    s16x4, *(const u32x2*)(Vc + (dt * 16 + li) * 72 + jt * 16 + quad * 4));
                oacc[0][dt] = MFMA1K(a0, bv, oacc[0][dt]);
                oacc[1][dt] = MFMA1K(a1, bv, oacc[1][dt]);
            }
            oacc[0][4] = MFMA1K(a0, ones, oacc[0][4]);
            oacc[1][4] = MFMA1K(a1, ones, oacc[1][4]);
        }

        // commit prefetched tile to the other buffer
        if (kt < 31) {
            u32x4* sk = (u32x4*)(Kt[cur ^ 1] + srow * 72 + scc);
            sk[0] = kreg[0];
            sk[1] = kreg[1];
            u32x4* sv = (u32x4*)(Vl[cur ^ 1] + srow * 72 + scc);
            sv[0] = vreg[0];
            sv[1] = vreg[1];
        }
    }

    // store bf16 partials + fp32 row-sums (normalization in k_out2)
#pragma unroll
    for (int rs = 0; rs < 2; ++rs) {
#pragma unroll
        for (int ct = 0; ct < 4; ++ct)
#pragma unroll
            for (int r = 0; r < 4; ++r) {
                int p = p0 + rbase + rs * 16 + quad * 4 + r;
                OP[((size_t)((ks * 8 + bh) * 4096 + p)) * 64 + ct * 16 + li] =
                    f2bf(oacc[rs][ct][r]);
            }
        if (li == 0) {
#pragma unroll
            for (int r = 0; r < 4; ++r) {
                int p = p0 + rbase + rs * 16 + quad * 4 + r;
                LS[(size_t)(ks * 8 + bh) * 4096 + p] = oacc[rs][4][r];
            }
        }
    }
}

// ---------------------------------------------------------------------------
// K4: fused combine + out-projection + residual. grid (64 pm, 2 b, 2 coh).
// Stage combined O tile [64p][256c] (bf16 partials, normalized), then 2 co-tiles.
__global__ __launch_bounds__(256) void k_out2(const u16* __restrict__ wob,
                                              const u16* __restrict__ OP,
                                              const float* __restrict__ LS,
                                              const float* __restrict__ x,
                                              float* __restrict__ out) {
    int pm = blockIdx.x, b = blockIdx.y, coh = blockIdx.z;
    int p0 = pm * 64;
    __shared__ __align__(16) u16 Bt[64 * 264];
    int t = threadIdx.x, wv = t >> 6, l = t & 63, quad = l >> 4, li = l & 15;

    {
        int row = t >> 2, head = t & 3;
        int bh = b * 4 + head;
        int p = p0 + row;
        const u32x4* o0p = (const u32x4*)(OP + ((size_t)(bh * 4096 + p)) * 64);
        const u32x4* o1p = (const u32x4*)(OP + ((size_t)((8 + bh) * 4096 + p)) * 64);
        float linv = 1.0f / (LS[(size_t)bh * 4096 + p] + LS[(size_t)(8 + bh) * 4096 + p]);
        u16* dst = Bt + row * 264 + head * 64;
#pragma unroll
        for (int kk = 0; kk < 8; ++kk) {  // 8 x u32x4 = 64 bf16 per row (FIX: was kk<2)
            u32x4 a = o0p[kk], c = o1p[kk];
            u32x4 pk;
            pk.x = pack2((bflo(a.x) + bflo(c.x)) * linv, (bfhi(a.x) + bfhi(c.x)) * linv);
            pk.y = pack2((bflo(a.y) + bflo(c.y)) * linv, (bfhi(a.y) + bfhi(c.y)) * linv);
            pk.z = pack2((bflo(a.z) + bflo(c.z)) * linv, (bfhi(a.z) + bfhi(c.z)) * linv);
            pk.w = pack2((bflo(a.w) + bflo(c.w)) * linv, (bfhi(a.w) + bfhi(c.w)) * linv);
            *(u32x4*)(dst + kk * 8) = pk;
        }
    }
    __syncthreads();

#pragma unroll
    for (int ci = 0; ci < 2; ++ci) {
        int com = coh * 2 + ci;
        int co0 = com * 64;
        f32x4 acc[4] = {{0, 0, 0, 0}, {0, 0, 0, 0}, {0, 0, 0, 0}, {0, 0, 0, 0}};
        const u32x4* arow = (const u32x4*)(wob + (size_t)(co0 + wv * 16 + li) * 256);
#pragma unroll
        for (int kc = 0; kc < 8; ++kc) {
            bf16x8 a = bc8(arow[kc * 4 + quad]);
#pragma unroll
            for (int ct = 0; ct < 4; ++ct) {
                bf16x8 bb = bc8(*(const u32x4*)(Bt + (ct * 16 + li) * 264 + kc * 32 + quad * 8));
                acc[ct] = MFMA16(a, bb, acc[ct]);
            }
        }
#pragma unroll
        for (int ct = 0; ct < 4; ++ct)
#pragma unroll
            for (int r = 0; r < 4; ++r) {
                size_t idx =
                    ((size_t)(b * 256 + co0 + wv * 16 + quad * 4 + r)) * 4096 + p0 + ct * 16 + li;
                out[idx] = acc[ct][r] + x[idx];
            }
    }
}

// ---------------------------------------------------------------------------
extern "C" void kernel_launch(void* const* d_in, const int* in_sizes, int n_in, void* d_out,
                              int out_size, void* d_ws, size_t ws_size, hipStream_t stream) {
    const float* x = (const float*)d_in[0];
    const float* wqkv = (const float*)d_in[1];
    const float* wout = (const float*)d_in[2];
    const float* relh = (const float*)d_in[3];
    const float* relw = (const float*)d_in[4];
    float* out = (float*)d_out;
    char* ws = (char*)d_ws;

    u16* xt = (u16*)(ws + 0);               // 4,194,304
    u16* wqb = (u16*)(ws + 4194304);        //   393,216
    u16* wob = (u16*)(ws + 4587520);        //   131,072
    u16* relwb = (u16*)(ws + 4718592);      //    16,384
    u16* relhb = (u16*)(ws + 4734976);      //    16,384
    u16* qb = (u16*)(ws + 4751360);         // 4,194,304
    u16* kb = (u16*)(ws + 8945664);         // 4,194,304
    u16* vtb = (u16*)(ws + 13139968);       // 4,194,304
    u16* Wabs = (u16*)(ws + 17334272);      // 4,194,304
    u16* Habs = (u16*)(ws + 21528576);      // 4,194,304
    u16* OPart = (u16*)(ws + 25722880);     // 8,388,608 (2 x 8 x 4096 x 64 bf16)
    float* LSum = (float*)(ws + 34111488);  //   262,144  end ~34.4 MB

    k_prep<<<768, 256, 0, stream>>>(x, wqkv, wout, relh, relw, xt, wqb, wob, relhb, relwb);
    k_qkv<<<dim3(64, 12, 2), 256, 0, stream>>>(xt, wqb, qb, kb, vtb);
    k_rel<<<dim3(64, 8, 2), 256, 0, stream>>>(qb, relwb, relhb, Wabs, Habs);
    k_flash<<<dim3(32, 8, 2), 256, 0, stream>>>(qb, kb, vtb, Wabs, Habs, OPart, LSum);
    k_out2<<<dim3(64, 2, 2), 256, 0, stream>>>(wob, OPart, LSum, x, out);
}